// Round 1
// baseline (2090.459 us; speedup 1.0000x reference)
//
#include <hip/hip_runtime.h>
#include <cstdint>

// Problem constants
#define BB 4
#define SS 4096
#define DD 1024
#define MM (BB * SS)          // 16384 tokens
#define BUDGET 2048           // BUDGET_K
// GEMM tiling
#define TM 64
#define TN 64
#define TK 32
#define LDT 68                // padded LDS leading dim (floats): 16B aligned, conflict-light

__device__ __forceinline__ float bf2f(unsigned short h) {
  return __uint_as_float(((unsigned int)h) << 16);
}
__device__ __forceinline__ unsigned short f2bf(float f) {
  unsigned int u = __float_as_uint(f);
  u = u + 0x7FFFu + ((u >> 16) & 1u);   // RNE
  return (unsigned short)(u >> 16);
}
// monotone float -> uint key (total order matching float compare; no NaNs in data)
__device__ __forceinline__ unsigned int sortkey(float f) {
  unsigned int b = __float_as_uint(f);
  return (b & 0x80000000u) ? ~b : (b | 0x80000000u);
}

__device__ __forceinline__ float blk_rsum_f(float v, float* red) {
  #pragma unroll
  for (int off = 1; off < 64; off <<= 1) v += __shfl_xor(v, off);
  const int wv = threadIdx.x >> 6;
  __syncthreads();
  if ((threadIdx.x & 63) == 0) red[wv] = v;
  __syncthreads();
  return red[0] + red[1] + red[2] + red[3];
}
__device__ __forceinline__ int blk_rsum_i(int v, int* redi) {
  #pragma unroll
  for (int off = 1; off < 64; off <<= 1) v += __shfl_xor(v, off);
  const int wv = threadIdx.x >> 6;
  __syncthreads();
  if ((threadIdx.x & 63) == 0) redi[wv] = v;
  __syncthreads();
  return redi[0] + redi[1] + redi[2] + redi[3];
}

// ---------------- Phase 1: out = x @ W^T (+bias, optional relu), store bf16 ----
// x [M,DD] f32 row-major, W [DD,DD] f32 row-major (out[m,n] = dot(x[m,:], W[n,:]))
__global__ __launch_bounds__(256) void gemm4_kernel(
    const float* __restrict__ x,
    const float* __restrict__ Wq, const float* __restrict__ Wk,
    const float* __restrict__ Wg, const float* __restrict__ Wm,
    const float* __restrict__ bg, const float* __restrict__ bm,
    unsigned short* __restrict__ qb, unsigned short* __restrict__ kb,
    unsigned short* __restrict__ gb, unsigned short* __restrict__ mb)
{
  __shared__ float xs[TK][LDT];   // transposed: xs[k][m]
  __shared__ float wsm[TK][LDT];  // transposed: wsm[k][n]
  const int mat = blockIdx.z;
  const float* __restrict__ W = (mat == 0) ? Wq : (mat == 1) ? Wk : (mat == 2) ? Wg : Wm;
  unsigned short* __restrict__ outp = (mat == 0) ? qb : (mat == 1) ? kb : (mat == 2) ? gb : mb;
  const int m0 = blockIdx.y * TM;
  const int n0 = blockIdx.x * TN;
  const int t  = threadIdx.x;
  const int ty = t >> 4, tx = t & 15;
  const int lr = t >> 3;            // 0..31
  const int lc = (t & 7) << 2;      // 0,4,...,28

  float acc[4][4] = {};
  for (int k0 = 0; k0 < DD; k0 += TK) {
    {
      float4 xv0 = *(const float4*)(x + (size_t)(m0 + lr) * DD + k0 + lc);
      float4 xv1 = *(const float4*)(x + (size_t)(m0 + lr + 32) * DD + k0 + lc);
      float4 wv0 = *(const float4*)(W + (size_t)(n0 + lr) * DD + k0 + lc);
      float4 wv1 = *(const float4*)(W + (size_t)(n0 + lr + 32) * DD + k0 + lc);
      xs[lc + 0][lr] = xv0.x; xs[lc + 1][lr] = xv0.y; xs[lc + 2][lr] = xv0.z; xs[lc + 3][lr] = xv0.w;
      xs[lc + 0][lr + 32] = xv1.x; xs[lc + 1][lr + 32] = xv1.y; xs[lc + 2][lr + 32] = xv1.z; xs[lc + 3][lr + 32] = xv1.w;
      wsm[lc + 0][lr] = wv0.x; wsm[lc + 1][lr] = wv0.y; wsm[lc + 2][lr] = wv0.z; wsm[lc + 3][lr] = wv0.w;
      wsm[lc + 0][lr + 32] = wv1.x; wsm[lc + 1][lr + 32] = wv1.y; wsm[lc + 2][lr + 32] = wv1.z; wsm[lc + 3][lr + 32] = wv1.w;
    }
    __syncthreads();
    #pragma unroll
    for (int kk = 0; kk < TK; ++kk) {
      const float4 av = *(const float4*)&xs[kk][ty << 2];
      const float4 bv = *(const float4*)&wsm[kk][tx << 2];
      const float a0 = av.x, a1 = av.y, a2 = av.z, a3 = av.w;
      const float b0 = bv.x, b1 = bv.y, b2 = bv.z, b3 = bv.w;
      acc[0][0] += a0 * b0; acc[0][1] += a0 * b1; acc[0][2] += a0 * b2; acc[0][3] += a0 * b3;
      acc[1][0] += a1 * b0; acc[1][1] += a1 * b1; acc[1][2] += a1 * b2; acc[1][3] += a1 * b3;
      acc[2][0] += a2 * b0; acc[2][1] += a2 * b1; acc[2][2] += a2 * b2; acc[2][3] += a2 * b3;
      acc[3][0] += a3 * b0; acc[3][1] += a3 * b1; acc[3][2] += a3 * b2; acc[3][3] += a3 * b3;
    }
    __syncthreads();
  }
  // epilogue
  #pragma unroll
  for (int i = 0; i < 4; ++i) {
    const int m = m0 + (ty << 2) + i;
    const int nb = n0 + (tx << 2);
    float v[4];
    #pragma unroll
    for (int j = 0; j < 4; ++j) {
      float vv = acc[i][j];
      if (mat == 2) vv += bg[nb + j];
      if (mat == 3) vv = fmaxf(vv + bm[nb + j], 0.0f);
      v[j] = vv;
    }
    ushort4 o;
    o.x = f2bf(v[0]); o.y = f2bf(v[1]); o.z = f2bf(v[2]); o.w = f2bf(v[3]);
    *(ushort4*)(outp + (size_t)m * DD + nb) = o;
  }
}

// ---------------- Phase 2: per-token gate/topk/twist/complexity + codebook probs
__global__ __launch_bounds__(256) void token_kernel(
    const float* __restrict__ x, const float* __restrict__ Wc,
    const unsigned short* __restrict__ qb, const unsigned short* __restrict__ kb,
    const unsigned short* __restrict__ gb, const unsigned short* __restrict__ mb,
    float* __restrict__ probs, float* __restrict__ craw)
{
  __shared__ float red[8];
  __shared__ int redi[8];
  __shared__ int eqpre[256];
  __shared__ float part[256 * 16];
  __shared__ float lsm[16];
  const int token = blockIdx.x;
  const int s = token & (SS - 1);
  const int t = threadIdx.x;
  const size_t rowo = (size_t)token * DD;
  const int d0 = t << 2;   // each thread owns features d0..d0+3

  // --- codebook logits: logit[j] = dot(x[token], Wc[j]) * 10 ---
  const float4 xv = *(const float4*)(x + rowo + d0);
  #pragma unroll
  for (int j = 0; j < 16; ++j) {
    const float* wr = Wc + j * DD + d0;
    part[t * 16 + j] = xv.x * wr[0] + xv.y * wr[1] + xv.z * wr[2] + xv.w * wr[3];
  }
  __syncthreads();
  if (t < 16) {
    float sj = 0.f;
    for (int r = 0; r < 256; ++r) sj += part[r * 16 + t];
    lsm[t] = sj * 10.0f;   // / CB_TEMP
  }
  __syncthreads();
  if (t == 0) {
    float p[16];
    float mx = -3.4e38f;
    #pragma unroll
    for (int j = 0; j < 16; ++j) mx = fmaxf(mx, lsm[j]);
    float se = 0.f;
    #pragma unroll
    for (int j = 0; j < 16; ++j) { p[j] = expf(lsm[j] - mx); se += p[j]; }
    const float inv = 1.0f / se;
    #pragma unroll
    for (int j = 0; j < 16; ++j) p[j] *= inv;
    // top-4 by value, ties -> lowest index (strict > keeps earliest max)
    unsigned int mk = 0;
    for (int it = 0; it < 4; ++it) {
      int bi = 0; float bv = -1.f;
      #pragma unroll
      for (int j = 0; j < 16; ++j)
        if (!((mk >> j) & 1u) && p[j] > bv) { bv = p[j]; bi = j; }
      mk |= 1u << bi;
    }
    float ssum = 0.f;
    #pragma unroll
    for (int j = 0; j < 16; ++j) if ((mk >> j) & 1u) ssum += p[j];
    const float rinv = 1.0f / fmaxf(ssum, 1e-8f);
    #pragma unroll
    for (int j = 0; j < 16; ++j)
      probs[(size_t)token * 16 + j] = ((mk >> j) & 1u) ? p[j] * rinv : 0.f;
  }

  if (s == 0) { if (t == 0) craw[token] = 0.f; return; }   // twist[0]=0 -> craw=0

  // --- adaptive top-k gate ---
  const ushort4 gu = *(const ushort4*)(gb + rowo + d0);
  float g[4] = { bf2f(gu.x), bf2f(gu.y), bf2f(gu.z), bf2f(gu.w) };
  const float asum = fabsf(g[0]) + fabsf(g[1]) + fabsf(g[2]) + fabsf(g[3]);
  const float tot = blk_rsum_f(asum, red);
  const float strength = tanhf(tot * (1.0f / 1024.0f));
  int kkv = (int)ceilf(strength * 256.0f);   // ADAPT_RATIO * D = 256
  kkv = min(max(kkv, 1), 1024);

  unsigned int key[4];
  #pragma unroll
  for (int i = 0; i < 4; ++i) key[i] = sortkey(g[i]);

  // binary search: largest T with count(key >= T) >= kkv  (T = kkv-th largest key)
  unsigned int lo = 0u, hi = 0xFFFFFFFFu;
  while (lo < hi) {
    const unsigned int mid = (unsigned int)(((unsigned long long)lo + hi + 1ull) >> 1);
    int c = (key[0] >= mid) + (key[1] >= mid) + (key[2] >= mid) + (key[3] >= mid);
    c = blk_rsum_i(c, redi);
    if (c >= kkv) lo = mid; else hi = mid - 1;
  }
  const unsigned int T = lo;
  int cg = (key[0] > T) + (key[1] > T) + (key[2] > T) + (key[3] > T);
  const int c_gt = blk_rsum_i(cg, redi);
  const int myeq = (key[0] == T) + (key[1] == T) + (key[2] == T) + (key[3] == T);
  eqpre[t] = myeq;
  __syncthreads();
  if (t == 0) {
    int run = 0;
    for (int r = 0; r < 256; ++r) { const int tmp = eqpre[r]; eqpre[r] = run; run += tmp; }
  }
  __syncthreads();
  int ebase = eqpre[t];
  const int keep_eq = kkv - c_gt;   // # of ==T elements kept, lowest index first

  // --- twist + complexity ---
  const ushort4 m4  = *(const ushort4*)(mb + rowo + d0);
  const ushort4 qc4 = *(const ushort4*)(qb + rowo + d0);
  const ushort4 kc4 = *(const ushort4*)(kb + rowo + d0);
  const ushort4 qp4 = *(const ushort4*)(qb + rowo - DD + d0);
  const ushort4 kp4 = *(const ushort4*)(kb + rowo - DD + d0);
  const float mg[4]  = { bf2f(m4.x),  bf2f(m4.y),  bf2f(m4.z),  bf2f(m4.w)  };
  const float qcf[4] = { bf2f(qc4.x), bf2f(qc4.y), bf2f(qc4.z), bf2f(qc4.w) };
  const float kcf[4] = { bf2f(kc4.x), bf2f(kc4.y), bf2f(kc4.z), bf2f(kc4.w) };
  const float qpf[4] = { bf2f(qp4.x), bf2f(qp4.y), bf2f(qp4.z), bf2f(qp4.w) };
  const float kpf[4] = { bf2f(kp4.x), bf2f(kp4.y), bf2f(kp4.z), bf2f(kp4.w) };

  float accv = 0.f;
  #pragma unroll
  for (int i = 0; i < 4; ++i) {
    const bool kp_ = (key[i] > T) || (key[i] == T && ebase < keep_eq);
    if (key[i] == T) ebase++;
    if ((g[i] > 0.0f) && kp_) {
      const float tw = qpf[i] * kcf[i] - qcf[i] * kpf[i];  // q[s-1]*k[s] - q[s]*k[s-1]
      accv += mg[i] * fabsf(tw);
    }
  }
  const float total = blk_rsum_f(accv, red);
  if (t == 0) craw[token] = total * (1.0f / 1024.0f);
}

// ---------------- Phase 3a: quorum sigmoid + codebook shift score ----------------
__global__ __launch_bounds__(256) void quorum_kernel(
    const float* __restrict__ craw, const float* __restrict__ probs,
    float* __restrict__ quorum, float* __restrict__ cb)
{
  const int idx = blockIdx.x * 256 + threadIdx.x;
  const int s = idx & (SS - 1);
  const float c1 = craw[idx];
  const float c0 = (s > 0) ? craw[idx - 1] : 0.f;
  const float c2 = (s < SS - 1) ? craw[idx + 1] : 0.f;
  const float local = (c0 + c1 + c2) / 3.0f;   // avg_pool, count_include_pad
  quorum[idx] = 1.0f / (1.0f + expf((0.5f - local) * 10.0f));
  float sh = 0.f;
  if (s > 0) {
    #pragma unroll
    for (int j = 0; j < 16; ++j)
      sh += fabsf(probs[(size_t)idx * 16 + j] - probs[(size_t)(idx - 1) * 16 + j]);
  }
  cb[idx] = 0.5f * sh;
}

// ---------------- Phase 3b: per-batch budget top-2048 + final mix ----------------
__global__ __launch_bounds__(64) void final_kernel(
    const float* __restrict__ craw, const float* __restrict__ quorum,
    const float* __restrict__ cb, float* __restrict__ outp)
{
  const int b = blockIdx.x;
  const int ln = threadIdx.x;   // one wave; lane owns s = ln*64 .. ln*64+63
  const size_t base = (size_t)b * SS;
  float qv[64]; unsigned int key[64];
  #pragma unroll
  for (int i = 0; i < 64; ++i) {
    qv[i] = quorum[base + ln * 64 + i];
    key[i] = sortkey(qv[i]);
  }
  unsigned int lo = 0u, hi = 0xFFFFFFFFu;
  while (lo < hi) {
    const unsigned int mid = (unsigned int)(((unsigned long long)lo + hi + 1ull) >> 1);
    int c = 0;
    #pragma unroll
    for (int i = 0; i < 64; ++i) c += (key[i] >= mid);
    #pragma unroll
    for (int off = 1; off < 64; off <<= 1) c += __shfl_xor(c, off);
    if (c >= BUDGET) lo = mid; else hi = mid - 1;
  }
  const unsigned int T = lo;
  int cg = 0, myeq = 0;
  #pragma unroll
  for (int i = 0; i < 64; ++i) { cg += (key[i] > T); myeq += (key[i] == T); }
  #pragma unroll
  for (int off = 1; off < 64; off <<= 1) cg += __shfl_xor(cg, off);
  int scan = myeq;
  #pragma unroll
  for (int off = 1; off < 64; off <<= 1) {
    const int nsc = __shfl_up(scan, off);
    if (ln >= off) scan += nsc;
  }
  int ebase = scan - myeq;          // exclusive prefix of ==T count, in index order
  const int keep_eq = BUDGET - cg;
  #pragma unroll
  for (int i = 0; i < 64; ++i) {
    const size_t sidx = base + (size_t)ln * 64 + i;
    const bool kp_ = (key[i] > T) || (key[i] == T && ebase < keep_eq);
    if (key[i] == T) ebase++;
    const float q = kp_ ? qv[i] : 0.f;
    // complexity*(0.5+0.5*quorum_masked)*0.7 + 0.3*cb_score
    outp[sidx] = 0.7f * (craw[sidx] * (0.5f + 0.5f * q)) + 0.3f * cb[sidx];
  }
}

extern "C" void kernel_launch(void* const* d_in, const int* in_sizes, int n_in,
                              void* d_out, int out_size, void* d_ws, size_t ws_size,
                              hipStream_t stream)
{
  const float* x  = (const float*)d_in[0];
  const float* Wq = (const float*)d_in[1];
  const float* Wk = (const float*)d_in[2];
  const float* Wg = (const float*)d_in[3];
  const float* bg = (const float*)d_in[4];
  const float* Wm = (const float*)d_in[5];
  const float* bm = (const float*)d_in[6];
  const float* Wc = (const float*)d_in[7];

  // workspace layout (needs ~136 MB)
  char* w = (char*)d_ws;
  unsigned short* qb = (unsigned short*)(w);                      // 33554432 B
  unsigned short* kb = (unsigned short*)(w + 33554432);           // 33554432 B
  unsigned short* gb = (unsigned short*)(w + 67108864);           // 33554432 B
  unsigned short* mb = (unsigned short*)(w + 100663296);          // 33554432 B
  float* probs  = (float*)(w + 134217728);                        // 1048576 B
  float* craw   = (float*)(w + 135266304);                        // 65536 B
  float* quorum = (float*)(w + 135331840);                        // 65536 B
  float* cbuf   = (float*)(w + 135397376);                        // 65536 B
  float* outp = (float*)d_out;

  gemm4_kernel<<<dim3(DD / TN, MM / TM, 4), 256, 0, stream>>>(
      x, Wq, Wk, Wg, Wm, bg, bm, qb, kb, gb, mb);
  token_kernel<<<dim3(MM), 256, 0, stream>>>(x, Wc, qb, kb, gb, mb, probs, craw);
  quorum_kernel<<<dim3(MM / 256), 256, 0, stream>>>(craw, probs, quorum, cbuf);
  final_kernel<<<dim3(BB), 64, 0, stream>>>(craw, quorum, cbuf, outp);
}

// Round 2
// 572.337 us; speedup vs baseline: 3.6525x; 3.6525x over previous
//
#include <hip/hip_runtime.h>
#include <hip/hip_bf16.h>
#include <cstdint>

// Problem constants
#define BB 4
#define SS 4096
#define DD 1024
#define MM (BB * SS)          // 16384 tokens
#define NTOT 4096             // 4 matrices * 1024 output features
#define BUDGET 2048

typedef __attribute__((ext_vector_type(8))) short short8v;   // 8 bf16 (4 VGPR)
typedef __attribute__((ext_vector_type(4))) float f32x4;

__device__ __forceinline__ float bf2f(unsigned short h) {
  return __uint_as_float(((unsigned int)h) << 16);
}
__device__ __forceinline__ unsigned short f2bf(float f) {
  unsigned int u = __float_as_uint(f);
  u = u + 0x7FFFu + ((u >> 16) & 1u);   // RNE
  return (unsigned short)(u >> 16);
}
// pack two f32 -> two bf16 (RNE) in one u32 (low = a.x)
__device__ __forceinline__ unsigned int pkbf(float lo, float hi) {
  float2 f; f.x = lo; f.y = hi;
  __hip_bfloat162 h = __float22bfloat162_rn(f);
  return *(unsigned int*)&h;
}
// monotone float -> uint key (total order matching float compare; no NaNs in data)
__device__ __forceinline__ unsigned int sortkey(float f) {
  unsigned int b = __float_as_uint(f);
  return (b & 0x80000000u) ? ~b : (b | 0x80000000u);
}

__device__ __forceinline__ float blk_rsum_f(float v, float* red) {
  #pragma unroll
  for (int off = 1; off < 64; off <<= 1) v += __shfl_xor(v, off);
  const int wv = threadIdx.x >> 6;
  __syncthreads();
  if ((threadIdx.x & 63) == 0) red[wv] = v;
  __syncthreads();
  return red[0] + red[1] + red[2] + red[3];
}
__device__ __forceinline__ int blk_rsum_i(int v, int* redi) {
  #pragma unroll
  for (int off = 1; off < 64; off <<= 1) v += __shfl_xor(v, off);
  const int wv = threadIdx.x >> 6;
  __syncthreads();
  if ((threadIdx.x & 63) == 0) redi[wv] = v;
  __syncthreads();
  return redi[0] + redi[1] + redi[2] + redi[3];
}

// ---------------- conversion: f32 -> bf16 copies of x and concat(Wq,Wk,Wg,Wm) ----
__global__ __launch_bounds__(256) void convert_kernel(
    const float* __restrict__ x,
    const float* __restrict__ Wq, const float* __restrict__ Wk,
    const float* __restrict__ Wg, const float* __restrict__ Wm,
    unsigned short* __restrict__ xb, unsigned short* __restrict__ Wb)
{
  const size_t NX = (size_t)MM * DD;          // 16777216
  const size_t NCH = (NX + 4u * 1048576u) / 4; // total float4 chunks = 5242880
  size_t i = (size_t)blockIdx.x * 256 + threadIdx.x;
  const size_t stride = (size_t)gridDim.x * 256;
  for (size_t c = i; c < NCH; c += stride) {
    const size_t e = c * 4;
    const float* src; unsigned short* dst;
    if (e < NX) { src = x + e; dst = xb + e; }
    else {
      const size_t w = e - NX;
      const int m = (int)(w >> 20);
      const float* Ws = (m == 0) ? Wq : (m == 1) ? Wk : (m == 2) ? Wg : Wm;
      src = Ws + (w & 1048575u); dst = Wb + w;
    }
    const float4 v = *(const float4*)src;
    uint2 o; o.x = pkbf(v.x, v.y); o.y = pkbf(v.z, v.w);
    *(uint2*)dst = o;
  }
}

// ---------------- MFMA GEMM: out[m, n] = sum_k x[m,k] * W[n,k]  (B^T layout) ----
// 128x128 tile, BK=32, 4 waves (2x2), 4x4 16x16x32 fragments per wave.
// DIRECT=1: bf16 inputs xb/Wb, global_load_lds staging.
// DIRECT=0: f32 inputs x/W*, reg-stage + in-flight f32->bf16 convert.
// F32OUT selects output element type (float vs bf16).
template<int DIRECT, int F32OUT>
__global__ __launch_bounds__(256) void mfma_gemm(
    const unsigned short* __restrict__ xb, const unsigned short* __restrict__ Wb,
    const float* __restrict__ x,
    const float* __restrict__ Wq, const float* __restrict__ Wk,
    const float* __restrict__ Wg, const float* __restrict__ Wm,
    const float* __restrict__ bg, const float* __restrict__ bm,
    void* __restrict__ q_o, void* __restrict__ k_o,
    void* __restrict__ g_o, void* __restrict__ m_o)
{
  __shared__ __align__(16) unsigned short As[128 * 32];  // 8 KB
  __shared__ __align__(16) unsigned short Bs[128 * 32];  // 8 KB
  const int t  = threadIdx.x;
  const int wv = t >> 6, ln = t & 63;
  const int wr = wv >> 1, wc = wv & 1;
  const int m0 = blockIdx.y * 128;
  const int n0 = blockIdx.x * 128;
  const int mat = n0 >> 10;
  const int nc0 = n0 & 1023;
  const float* __restrict__ Wsrc = (mat == 0) ? Wq : (mat == 1) ? Wk : (mat == 2) ? Wg : Wm;

  f32x4 acc[4][4];
  #pragma unroll
  for (int i = 0; i < 4; ++i)
    #pragma unroll
    for (int j = 0; j < 4; ++j) { acc[i][j][0] = 0.f; acc[i][j][1] = 0.f; acc[i][j][2] = 0.f; acc[i][j][3] = 0.f; }

  const int frow = ln & 15;   // fragment row (A) / col (B)
  const int kc   = ln >> 4;   // k-chunk of 8

  for (int k0 = 0; k0 < DD; k0 += 32) {
    if constexpr (DIRECT) {
      #pragma unroll
      for (int c = 0; c < 2; ++c) {
        const int i = c * 256 + t;
        const unsigned short* ga = xb + (size_t)(m0 + (i >> 2)) * DD + k0 + ((i & 3) << 3);
        const unsigned short* gw = Wb + (size_t)(n0 + (i >> 2)) * DD + k0 + ((i & 3) << 3);
        __builtin_amdgcn_global_load_lds(
            (const __attribute__((address_space(1))) void*)ga,
            (__attribute__((address_space(3))) void*)((__attribute__((address_space(3))) char*)As + c * 4096 + wv * 1024),
            16, 0, 0);
        __builtin_amdgcn_global_load_lds(
            (const __attribute__((address_space(1))) void*)gw,
            (__attribute__((address_space(3))) void*)((__attribute__((address_space(3))) char*)Bs + c * 4096 + wv * 1024),
            16, 0, 0);
      }
    } else {
      #pragma unroll
      for (int c = 0; c < 2; ++c) {
        const int i = c * 256 + t;
        const int row = i >> 2, colc = i & 3;       // dest: 8 bf16 at As[row*32 + colc*8]
        const float* ga = x    + (size_t)(m0 + row) * DD + k0 + (colc << 3);
        const float* gw = Wsrc + (size_t)(nc0 + row) * DD + k0 + (colc << 3);
        const float4 a0 = *(const float4*)ga, a1 = *(const float4*)(ga + 4);
        const float4 b0 = *(const float4*)gw, b1 = *(const float4*)(gw + 4);
        uint4 ao, bo;
        ao.x = pkbf(a0.x, a0.y); ao.y = pkbf(a0.z, a0.w);
        ao.z = pkbf(a1.x, a1.y); ao.w = pkbf(a1.z, a1.w);
        bo.x = pkbf(b0.x, b0.y); bo.y = pkbf(b0.z, b0.w);
        bo.z = pkbf(b1.x, b1.y); bo.w = pkbf(b1.z, b1.w);
        *(uint4*)&As[row * 32 + colc * 8] = ao;
        *(uint4*)&Bs[row * 32 + colc * 8] = bo;
      }
    }
    __syncthreads();

    short8v a[4], b[4];
    #pragma unroll
    for (int i = 0; i < 4; ++i) {
      a[i] = *(const short8v*)&As[(wr * 64 + i * 16 + frow) * 32 + kc * 8];
      b[i] = *(const short8v*)&Bs[(wc * 64 + i * 16 + frow) * 32 + kc * 8];
    }
    #pragma unroll
    for (int i = 0; i < 4; ++i)
      #pragma unroll
      for (int j = 0; j < 4; ++j)
        acc[i][j] = __builtin_amdgcn_mfma_f32_16x16x32_bf16(a[i], b[j], acc[i][j], 0, 0, 0);
    __syncthreads();
  }

  // epilogue: bias (mat 2), relu+bias (mat 3), store
  void* outp = (mat == 0) ? q_o : (mat == 1) ? k_o : (mat == 2) ? g_o : m_o;
  #pragma unroll
  for (int i = 0; i < 4; ++i) {
    #pragma unroll
    for (int j = 0; j < 4; ++j) {
      const int col = nc0 + wc * 64 + j * 16 + frow;
      #pragma unroll
      for (int r = 0; r < 4; ++r) {
        const int row = m0 + wr * 64 + i * 16 + kc * 4 + r;
        float v = acc[i][j][r];
        if (mat == 2) v += bg[col];
        if (mat == 3) v = fmaxf(v + bm[col], 0.0f);
        if constexpr (F32OUT) ((float*)outp)[(size_t)row * DD + col] = v;
        else ((unsigned short*)outp)[(size_t)row * DD + col] = f2bf(v);
      }
    }
  }
}

// ---------------- Phase 2: per-token gate/topk/twist/complexity + codebook probs
template<int F32>
__device__ __forceinline__ void ld4v(const void* p, size_t i, float o[4]) {
  if constexpr (F32) {
    const float4 v = *(const float4*)((const float*)p + i);
    o[0] = v.x; o[1] = v.y; o[2] = v.z; o[3] = v.w;
  } else {
    const ushort4 u = *(const ushort4*)((const unsigned short*)p + i);
    o[0] = bf2f(u.x); o[1] = bf2f(u.y); o[2] = bf2f(u.z); o[3] = bf2f(u.w);
  }
}

template<int F32>
__global__ __launch_bounds__(256) void token_kernel(
    const float* __restrict__ x, const float* __restrict__ Wc,
    const void* __restrict__ qb, const void* __restrict__ kb,
    const void* __restrict__ gb, const void* __restrict__ mb,
    float* __restrict__ probs, float* __restrict__ craw)
{
  __shared__ float red[8];
  __shared__ int redi[8];
  __shared__ int eqpre[256];
  __shared__ float part[256 * 16];
  __shared__ float lsm[16];
  const int token = blockIdx.x;
  const int s = token & (SS - 1);
  const int t = threadIdx.x;
  const size_t rowo = (size_t)token * DD;
  const int d0 = t << 2;

  // --- codebook logits ---
  const float4 xv = *(const float4*)(x + rowo + d0);
  #pragma unroll
  for (int j = 0; j < 16; ++j) {
    const float* wr = Wc + j * DD + d0;
    part[t * 16 + j] = xv.x * wr[0] + xv.y * wr[1] + xv.z * wr[2] + xv.w * wr[3];
  }
  __syncthreads();
  if (t < 16) {
    float sj = 0.f;
    for (int r = 0; r < 256; ++r) sj += part[r * 16 + t];
    lsm[t] = sj * 10.0f;
  }
  __syncthreads();
  if (t == 0) {
    float p[16];
    float mx = -3.4e38f;
    #pragma unroll
    for (int j = 0; j < 16; ++j) mx = fmaxf(mx, lsm[j]);
    float se = 0.f;
    #pragma unroll
    for (int j = 0; j < 16; ++j) { p[j] = expf(lsm[j] - mx); se += p[j]; }
    const float inv = 1.0f / se;
    #pragma unroll
    for (int j = 0; j < 16; ++j) p[j] *= inv;
    unsigned int mk = 0;
    for (int it = 0; it < 4; ++it) {
      int bi = 0; float bv = -1.f;
      #pragma unroll
      for (int j = 0; j < 16; ++j)
        if (!((mk >> j) & 1u) && p[j] > bv) { bv = p[j]; bi = j; }
      mk |= 1u << bi;
    }
    float ssum = 0.f;
    #pragma unroll
    for (int j = 0; j < 16; ++j) if ((mk >> j) & 1u) ssum += p[j];
    const float rinv = 1.0f / fmaxf(ssum, 1e-8f);
    #pragma unroll
    for (int j = 0; j < 16; ++j)
      probs[(size_t)token * 16 + j] = ((mk >> j) & 1u) ? p[j] * rinv : 0.f;
  }

  if (s == 0) { if (t == 0) craw[token] = 0.f; return; }

  // --- adaptive top-k gate ---
  float g[4];
  ld4v<F32>(gb, rowo + d0, g);
  const float asum = fabsf(g[0]) + fabsf(g[1]) + fabsf(g[2]) + fabsf(g[3]);
  const float tot = blk_rsum_f(asum, red);
  const float strength = tanhf(tot * (1.0f / 1024.0f));
  int kkv = (int)ceilf(strength * 256.0f);
  kkv = min(max(kkv, 1), 1024);

  unsigned int key[4];
  #pragma unroll
  for (int i = 0; i < 4; ++i) key[i] = sortkey(g[i]);

  unsigned int lo = 0u, hi = 0xFFFFFFFFu;
  while (lo < hi) {
    const unsigned int mid = (unsigned int)(((unsigned long long)lo + hi + 1ull) >> 1);
    int c = (key[0] >= mid) + (key[1] >= mid) + (key[2] >= mid) + (key[3] >= mid);
    c = blk_rsum_i(c, redi);
    if (c >= kkv) lo = mid; else hi = mid - 1;
  }
  const unsigned int T = lo;
  int cg = (key[0] > T) + (key[1] > T) + (key[2] > T) + (key[3] > T);
  const int c_gt = blk_rsum_i(cg, redi);
  const int myeq = (key[0] == T) + (key[1] == T) + (key[2] == T) + (key[3] == T);
  eqpre[t] = myeq;
  __syncthreads();
  if (t == 0) {
    int run = 0;
    for (int r = 0; r < 256; ++r) { const int tmp = eqpre[r]; eqpre[r] = run; run += tmp; }
  }
  __syncthreads();
  int ebase = eqpre[t];
  const int keep_eq = kkv - c_gt;

  float mg[4], qcf[4], kcf[4], qpf[4], kpf[4];
  ld4v<F32>(mb, rowo + d0, mg);
  ld4v<F32>(qb, rowo + d0, qcf);
  ld4v<F32>(kb, rowo + d0, kcf);
  ld4v<F32>(qb, rowo - DD + d0, qpf);
  ld4v<F32>(kb, rowo - DD + d0, kpf);

  float accv = 0.f;
  #pragma unroll
  for (int i = 0; i < 4; ++i) {
    const bool kp_ = (key[i] > T) || (key[i] == T && ebase < keep_eq);
    if (key[i] == T) ebase++;
    if ((g[i] > 0.0f) && kp_) {
      const float tw = qpf[i] * kcf[i] - qcf[i] * kpf[i];
      accv += mg[i] * fabsf(tw);
    }
  }
  const float total = blk_rsum_f(accv, red);
  if (t == 0) craw[token] = total * (1.0f / 1024.0f);
}

// ---------------- Phase 3a: quorum sigmoid + codebook shift score ----------------
__global__ __launch_bounds__(256) void quorum_kernel(
    const float* __restrict__ craw, const float* __restrict__ probs,
    float* __restrict__ quorum, float* __restrict__ cb)
{
  const int idx = blockIdx.x * 256 + threadIdx.x;
  const int s = idx & (SS - 1);
  const float c1 = craw[idx];
  const float c0 = (s > 0) ? craw[idx - 1] : 0.f;
  const float c2 = (s < SS - 1) ? craw[idx + 1] : 0.f;
  const float local = (c0 + c1 + c2) / 3.0f;
  quorum[idx] = 1.0f / (1.0f + expf((0.5f - local) * 10.0f));
  float sh = 0.f;
  if (s > 0) {
    #pragma unroll
    for (int j = 0; j < 16; ++j)
      sh += fabsf(probs[(size_t)idx * 16 + j] - probs[(size_t)(idx - 1) * 16 + j]);
  }
  cb[idx] = 0.5f * sh;
}

// ---------------- Phase 3b: per-batch budget top-2048 + final mix ----------------
__global__ __launch_bounds__(64) void final_kernel(
    const float* __restrict__ craw, const float* __restrict__ quorum,
    const float* __restrict__ cb, float* __restrict__ outp)
{
  const int b = blockIdx.x;
  const int ln = threadIdx.x;
  const size_t base = (size_t)b * SS;
  float qv[64]; unsigned int key[64];
  #pragma unroll
  for (int i = 0; i < 64; ++i) {
    qv[i] = quorum[base + ln * 64 + i];
    key[i] = sortkey(qv[i]);
  }
  unsigned int lo = 0u, hi = 0xFFFFFFFFu;
  while (lo < hi) {
    const unsigned int mid = (unsigned int)(((unsigned long long)lo + hi + 1ull) >> 1);
    int c = 0;
    #pragma unroll
    for (int i = 0; i < 64; ++i) c += (key[i] >= mid);
    #pragma unroll
    for (int off = 1; off < 64; off <<= 1) c += __shfl_xor(c, off);
    if (c >= BUDGET) lo = mid; else hi = mid - 1;
  }
  const unsigned int T = lo;
  int cg = 0, myeq = 0;
  #pragma unroll
  for (int i = 0; i < 64; ++i) { cg += (key[i] > T); myeq += (key[i] == T); }
  #pragma unroll
  for (int off = 1; off < 64; off <<= 1) cg += __shfl_xor(cg, off);
  int scan = myeq;
  #pragma unroll
  for (int off = 1; off < 64; off <<= 1) {
    const int nsc = __shfl_up(scan, off);
    if (ln >= off) scan += nsc;
  }
  int ebase = scan - myeq;
  const int keep_eq = BUDGET - cg;
  #pragma unroll
  for (int i = 0; i < 64; ++i) {
    const size_t sidx = base + (size_t)ln * 64 + i;
    const bool kp_ = (key[i] > T) || (key[i] == T && ebase < keep_eq);
    if (key[i] == T) ebase++;
    const float q = kp_ ? qv[i] : 0.f;
    outp[sidx] = 0.7f * (craw[sidx] * (0.5f + 0.5f * q)) + 0.3f * cb[sidx];
  }
}

extern "C" void kernel_launch(void* const* d_in, const int* in_sizes, int n_in,
                              void* d_out, int out_size, void* d_ws, size_t ws_size,
                              hipStream_t stream)
{
  const float* x  = (const float*)d_in[0];
  const float* Wq = (const float*)d_in[1];
  const float* Wk = (const float*)d_in[2];
  const float* Wg = (const float*)d_in[3];
  const float* bg = (const float*)d_in[4];
  const float* Wm = (const float*)d_in[5];
  const float* bm = (const float*)d_in[6];
  const float* Wc = (const float*)d_in[7];
  float* outp = (float*)d_out;
  char* w = (char*)d_ws;

  const size_t SZ_F32 = (size_t)MM * DD * 4;   // 64 MB per f32 intermediate
  const size_t SZ_BF  = (size_t)MM * DD * 2;   // 32 MB per bf16 intermediate
  const size_t SZ_SMALL = 1048576 + 3 * 65536; // probs + craw/quorum/cb
  const size_t need_roomy = 4 * SZ_F32 + SZ_SMALL + SZ_BF /*xb*/ + (size_t)4 * 1048576 * 2 /*Wb*/;
  const bool roomy = ws_size >= need_roomy;

  if (roomy) {
    float* qf = (float*)(w);
    float* kf = (float*)(w + SZ_F32);
    float* gf = (float*)(w + 2 * SZ_F32);
    float* mf = (float*)(w + 3 * SZ_F32);
    char* sm = w + 4 * SZ_F32;
    float* probs  = (float*)(sm);
    float* craw   = (float*)(sm + 1048576);
    float* quorum = (float*)(sm + 1048576 + 65536);
    float* cbuf   = (float*)(sm + 1048576 + 2 * 65536);
    unsigned short* xb = (unsigned short*)(sm + SZ_SMALL);
    unsigned short* Wb = xb + (size_t)MM * DD;

    convert_kernel<<<2048, 256, 0, stream>>>(x, Wq, Wk, Wg, Wm, xb, Wb);
    mfma_gemm<1, 1><<<dim3(NTOT / 128, MM / 128), 256, 0, stream>>>(
        xb, Wb, x, Wq, Wk, Wg, Wm, bg, bm, qf, kf, gf, mf);
    token_kernel<1><<<dim3(MM), 256, 0, stream>>>(x, Wc, qf, kf, gf, mf, probs, craw);
    quorum_kernel<<<dim3(MM / 256), 256, 0, stream>>>(craw, probs, quorum, cbuf);
    final_kernel<<<dim3(BB), 64, 0, stream>>>(craw, quorum, cbuf, outp);
  } else {
    // proven 135.46 MB footprint: bf16 intermediates, in-GEMM f32->bf16 conversion
    unsigned short* qb = (unsigned short*)(w);
    unsigned short* kb = (unsigned short*)(w + SZ_BF);
    unsigned short* gb = (unsigned short*)(w + 2 * SZ_BF);
    unsigned short* mb = (unsigned short*)(w + 3 * SZ_BF);
    char* sm = w + 4 * SZ_BF;
    float* probs  = (float*)(sm);
    float* craw   = (float*)(sm + 1048576);
    float* quorum = (float*)(sm + 1048576 + 65536);
    float* cbuf   = (float*)(sm + 1048576 + 2 * 65536);

    mfma_gemm<0, 0><<<dim3(NTOT / 128, MM / 128), 256, 0, stream>>>(
        nullptr, nullptr, x, Wq, Wk, Wg, Wm, bg, bm, qb, kb, gb, mb);
    token_kernel<0><<<dim3(MM), 256, 0, stream>>>(x, Wc, qb, kb, gb, mb, probs, craw);
    quorum_kernel<<<dim3(MM / 256), 256, 0, stream>>>(craw, probs, quorum, cbuf);
    final_kernel<<<dim3(BB), 64, 0, stream>>>(craw, quorum, cbuf, outp);
  }
}

// Round 3
// 409.729 us; speedup vs baseline: 5.1020x; 1.3969x over previous
//
#include <hip/hip_runtime.h>
#include <hip/hip_bf16.h>
#include <cstdint>

// Problem constants
#define BB 4
#define SS 4096
#define DD 1024
#define MM (BB * SS)          // 16384 tokens
#define NTOT 4096             // 4 matrices * 1024 output features
#define BUDGET 2048

typedef __attribute__((ext_vector_type(8))) short short8v;   // 8 bf16 (4 VGPR)
typedef __attribute__((ext_vector_type(4))) float f32x4;

__device__ __forceinline__ float bf2f(unsigned int h) {
  return __uint_as_float(h << 16);
}
__device__ __forceinline__ unsigned short f2bf(float f) {
  unsigned int u = __float_as_uint(f);
  u = u + 0x7FFFu + ((u >> 16) & 1u);   // RNE
  return (unsigned short)(u >> 16);
}
// pack two f32 -> two bf16 (RNE) in one u32 (low = a.x)
__device__ __forceinline__ unsigned int pkbf(float lo, float hi) {
  float2 f; f.x = lo; f.y = hi;
  __hip_bfloat162 h = __float22bfloat162_rn(f);
  return *(unsigned int*)&h;
}

// ---------------- conversion: f32 -> bf16 copies of x and concat(Wq,Wk,Wg,Wm) ----
__global__ __launch_bounds__(256) void convert_kernel(
    const float* __restrict__ x,
    const float* __restrict__ Wq, const float* __restrict__ Wk,
    const float* __restrict__ Wg, const float* __restrict__ Wm,
    unsigned short* __restrict__ xb, unsigned short* __restrict__ Wb)
{
  const size_t NX = (size_t)MM * DD;           // 16777216
  const size_t NCH = (NX + 4u * 1048576u) / 4; // total float4 chunks = 5242880
  size_t i = (size_t)blockIdx.x * 256 + threadIdx.x;
  const size_t stride = (size_t)gridDim.x * 256;
  for (size_t c = i; c < NCH; c += stride) {
    const size_t e = c * 4;
    const float* src; unsigned short* dst;
    if (e < NX) { src = x + e; dst = xb + e; }
    else {
      const size_t w = e - NX;
      const int m = (int)(w >> 20);
      const float* Ws = (m == 0) ? Wq : (m == 1) ? Wk : (m == 2) ? Wg : Wm;
      src = Ws + (w & 1048575u); dst = Wb + w;
    }
    const float4 v = *(const float4*)src;
    uint2 o; o.x = pkbf(v.x, v.y); o.y = pkbf(v.z, v.w);
    *(uint2*)dst = o;
  }
}

// ---------------- MFMA GEMM: out[m, n] = sum_k x[m,k] * W[n,k]  (B^T layout) ----
// 128x128 tile, BK=32, 4 waves (2x2), 4x4 16x16x32 fragments per wave.
// DIRECT=1: bf16 inputs xb/Wb, global_load_lds staging (m97 structure).
// DIRECT=0: f32 inputs x/W*, reg-stage + in-flight f32->bf16 convert.
template<int DIRECT, int F32OUT>
__global__ __launch_bounds__(256) void mfma_gemm(
    const unsigned short* __restrict__ xb, const unsigned short* __restrict__ Wb,
    const float* __restrict__ x,
    const float* __restrict__ Wq, const float* __restrict__ Wk,
    const float* __restrict__ Wg, const float* __restrict__ Wm,
    const float* __restrict__ bg, const float* __restrict__ bm,
    void* __restrict__ q_o, void* __restrict__ k_o,
    void* __restrict__ g_o, void* __restrict__ m_o)
{
  __shared__ __align__(16) unsigned short As[128 * 32];  // 8 KB
  __shared__ __align__(16) unsigned short Bs[128 * 32];  // 8 KB
  const int t  = threadIdx.x;
  const int wv = t >> 6, ln = t & 63;
  const int wr = wv >> 1, wc = wv & 1;
  const int m0 = blockIdx.y * 128;
  const int n0 = blockIdx.x * 128;
  const int mat = n0 >> 10;
  const int nc0 = n0 & 1023;
  const float* __restrict__ Wsrc = (mat == 0) ? Wq : (mat == 1) ? Wk : (mat == 2) ? Wg : Wm;

  f32x4 acc[4][4];
  #pragma unroll
  for (int i = 0; i < 4; ++i)
    #pragma unroll
    for (int j = 0; j < 4; ++j) { acc[i][j][0] = 0.f; acc[i][j][1] = 0.f; acc[i][j][2] = 0.f; acc[i][j][3] = 0.f; }

  const int frow = ln & 15;   // fragment row (A) / col (B)
  const int kc   = ln >> 4;   // k-chunk of 8

  for (int k0 = 0; k0 < DD; k0 += 32) {
    if constexpr (DIRECT) {
      #pragma unroll
      for (int c = 0; c < 2; ++c) {
        const int i = c * 256 + t;
        const unsigned short* ga = xb + (size_t)(m0 + (i >> 2)) * DD + k0 + ((i & 3) << 3);
        const unsigned short* gw = Wb + (size_t)(n0 + (i >> 2)) * DD + k0 + ((i & 3) << 3);
        __builtin_amdgcn_global_load_lds(
            (const __attribute__((address_space(1))) void*)ga,
            (__attribute__((address_space(3))) void*)((__attribute__((address_space(3))) char*)As + c * 4096 + wv * 1024),
            16, 0, 0);
        __builtin_amdgcn_global_load_lds(
            (const __attribute__((address_space(1))) void*)gw,
            (__attribute__((address_space(3))) void*)((__attribute__((address_space(3))) char*)Bs + c * 4096 + wv * 1024),
            16, 0, 0);
      }
    } else {
      #pragma unroll
      for (int c = 0; c < 2; ++c) {
        const int i = c * 256 + t;
        const int row = i >> 2, colc = i & 3;
        const float* ga = x    + (size_t)(m0 + row) * DD + k0 + (colc << 3);
        const float* gw = Wsrc + (size_t)(nc0 + row) * DD + k0 + (colc << 3);
        const float4 a0 = *(const float4*)ga, a1 = *(const float4*)(ga + 4);
        const float4 b0 = *(const float4*)gw, b1 = *(const float4*)(gw + 4);
        uint4 ao, bo;
        ao.x = pkbf(a0.x, a0.y); ao.y = pkbf(a0.z, a0.w);
        ao.z = pkbf(a1.x, a1.y); ao.w = pkbf(a1.z, a1.w);
        bo.x = pkbf(b0.x, b0.y); bo.y = pkbf(b0.z, b0.w);
        bo.z = pkbf(b1.x, b1.y); bo.w = pkbf(b1.z, b1.w);
        *(uint4*)&As[row * 32 + colc * 8] = ao;
        *(uint4*)&Bs[row * 32 + colc * 8] = bo;
      }
    }
    __syncthreads();

    short8v a[4], b[4];
    #pragma unroll
    for (int i = 0; i < 4; ++i) {
      a[i] = *(const short8v*)&As[(wr * 64 + i * 16 + frow) * 32 + kc * 8];
      b[i] = *(const short8v*)&Bs[(wc * 64 + i * 16 + frow) * 32 + kc * 8];
    }
    #pragma unroll
    for (int i = 0; i < 4; ++i)
      #pragma unroll
      for (int j = 0; j < 4; ++j)
        acc[i][j] = __builtin_amdgcn_mfma_f32_16x16x32_bf16(a[i], b[j], acc[i][j], 0, 0, 0);
    __syncthreads();
  }

  void* outp = (mat == 0) ? q_o : (mat == 1) ? k_o : (mat == 2) ? g_o : m_o;
  #pragma unroll
  for (int i = 0; i < 4; ++i) {
    #pragma unroll
    for (int j = 0; j < 4; ++j) {
      const int col = nc0 + wc * 64 + j * 16 + frow;
      #pragma unroll
      for (int r = 0; r < 4; ++r) {
        const int row = m0 + wr * 64 + i * 16 + kc * 4 + r;
        float v = acc[i][j][r];
        if (mat == 2) v += bg[col];
        if (mat == 3) v = fmaxf(v + bm[col], 0.0f);
        if constexpr (F32OUT) ((float*)outp)[(size_t)row * DD + col] = v;
        else ((unsigned short*)outp)[(size_t)row * DD + col] = f2bf(v);
      }
    }
  }
}

// ---------------- Phase 2: wave-per-token, zero barriers ----------------
// Wave handles one token. Codebook: lane owns 4 float4 chunks (d = e*256+ln*4).
// Gate/twist: lane owns contiguous d in [ln*16, ln*16+16) -> stable tie order via
// wave prefix scan. Keys are 16-bit (bf16-derived) -> 16-iteration threshold search.
__global__ __launch_bounds__(256) void token_kernel2(
    const float* __restrict__ x, const float* __restrict__ Wc,
    const unsigned short* __restrict__ qb, const unsigned short* __restrict__ kb,
    const unsigned short* __restrict__ gb, const unsigned short* __restrict__ mb,
    float* __restrict__ probs, float* __restrict__ craw)
{
  const int wv = threadIdx.x >> 6;
  const int ln = threadIdx.x & 63;
  const int token = blockIdx.x * 4 + wv;
  const int s = token & (SS - 1);
  const size_t rowo = (size_t)token * DD;

  // --- codebook logits: per-lane partials over disjoint d, butterfly reduce ---
  const float4* x4 = (const float4*)(x + rowo);
  const float4* Wc4 = (const float4*)Wc;
  float4 xv[4];
  #pragma unroll
  for (int e = 0; e < 4; ++e) xv[e] = x4[e * 64 + ln];
  float pj[16];
  #pragma unroll
  for (int j = 0; j < 16; ++j) {
    float a = 0.f;
    #pragma unroll
    for (int e = 0; e < 4; ++e) {
      const float4 w = Wc4[j * 256 + e * 64 + ln];
      a += xv[e].x * w.x + xv[e].y * w.y + xv[e].z * w.z + xv[e].w * w.w;
    }
    pj[j] = a;
  }
  #pragma unroll
  for (int j = 0; j < 16; ++j) {
    #pragma unroll
    for (int off = 1; off < 64; off <<= 1) pj[j] += __shfl_xor(pj[j], off);
  }
  if (ln == 0) {
    float p[16];
    float mx = -3.4e38f;
    #pragma unroll
    for (int j = 0; j < 16; ++j) { p[j] = pj[j] * 10.0f; mx = fmaxf(mx, p[j]); }
    float se = 0.f;
    #pragma unroll
    for (int j = 0; j < 16; ++j) { p[j] = expf(p[j] - mx); se += p[j]; }
    const float inv = 1.0f / se;
    #pragma unroll
    for (int j = 0; j < 16; ++j) p[j] *= inv;
    unsigned int mk = 0;
    for (int it = 0; it < 4; ++it) {
      int bi = 0; float bv = -1.f;
      #pragma unroll
      for (int j = 0; j < 16; ++j)
        if (!((mk >> j) & 1u) && p[j] > bv) { bv = p[j]; bi = j; }
      mk |= 1u << bi;
    }
    float ssum = 0.f;
    #pragma unroll
    for (int j = 0; j < 16; ++j) if ((mk >> j) & 1u) ssum += p[j];
    const float rinv = 1.0f / fmaxf(ssum, 1e-8f);
    #pragma unroll
    for (int j = 0; j < 16; ++j)
      probs[(size_t)token * 16 + j] = ((mk >> j) & 1u) ? p[j] * rinv : 0.f;
  }

  if (s == 0) { if (ln == 0) craw[token] = 0.f; return; }

  // --- adaptive top-k gate: 16-bit keys from bf16 bits ---
  unsigned short gbit[16];
  *(uint4*)&gbit[0] = *(const uint4*)(gb + rowo + ln * 16);
  *(uint4*)&gbit[8] = *(const uint4*)(gb + rowo + ln * 16 + 8);
  int ckey[16];
  float asum = 0.f;
  #pragma unroll
  for (int i = 0; i < 16; ++i) {
    const unsigned int b = gbit[i];
    ckey[i] = (b & 0x8000u) ? (int)(b ^ 0xFFFFu) : (int)(b | 0x8000u);
    asum += bf2f(b & 0x7FFFu);
  }
  #pragma unroll
  for (int off = 1; off < 64; off <<= 1) asum += __shfl_xor(asum, off);
  const float strength = tanhf(asum * (1.0f / 1024.0f));
  int kkv = (int)ceilf(strength * 256.0f);
  kkv = min(max(kkv, 1), 1024);

  // binary search over 16-bit key space: largest T with count(key >= T) >= kkv
  int lo = 0, hi = 0xFFFF;
  while (lo < hi) {
    const int mid = (lo + hi + 1) >> 1;
    int c = 0;
    #pragma unroll
    for (int i = 0; i < 16; ++i) c += (ckey[i] >= mid);
    #pragma unroll
    for (int off = 1; off < 64; off <<= 1) c += __shfl_xor(c, off);
    if (c >= kkv) lo = mid; else hi = mid - 1;
  }
  const int T = lo;

  int cg = 0, myeq = 0;
  #pragma unroll
  for (int i = 0; i < 16; ++i) { cg += (ckey[i] > T); myeq += (ckey[i] == T); }
  #pragma unroll
  for (int off = 1; off < 64; off <<= 1) cg += __shfl_xor(cg, off);
  int incl = myeq;
  #pragma unroll
  for (int off = 1; off < 64; off <<= 1) {
    const int tt = __shfl_up(incl, off);
    if (ln >= off) incl += tt;
  }
  int ebase = incl - myeq;          // exclusive prefix of ==T count, feature order
  const int keep_eq = kkv - cg;

  // --- twist + complexity ---
  unsigned short mB[16], qcB[16], kcB[16], qpB[16], kpB[16];
  *(uint4*)&mB[0]  = *(const uint4*)(mb + rowo + ln * 16);
  *(uint4*)&mB[8]  = *(const uint4*)(mb + rowo + ln * 16 + 8);
  *(uint4*)&qcB[0] = *(const uint4*)(qb + rowo + ln * 16);
  *(uint4*)&qcB[8] = *(const uint4*)(qb + rowo + ln * 16 + 8);
  *(uint4*)&kcB[0] = *(const uint4*)(kb + rowo + ln * 16);
  *(uint4*)&kcB[8] = *(const uint4*)(kb + rowo + ln * 16 + 8);
  *(uint4*)&qpB[0] = *(const uint4*)(qb + rowo - DD + ln * 16);
  *(uint4*)&qpB[8] = *(const uint4*)(qb + rowo - DD + ln * 16 + 8);
  *(uint4*)&kpB[0] = *(const uint4*)(kb + rowo - DD + ln * 16);
  *(uint4*)&kpB[8] = *(const uint4*)(kb + rowo - DD + ln * 16 + 8);

  float accv = 0.f;
  #pragma unroll
  for (int i = 0; i < 16; ++i) {
    const bool kp_ = (ckey[i] > T) || (ckey[i] == T && ebase < keep_eq);
    if (ckey[i] == T) ebase++;
    const unsigned int b = gbit[i];
    const bool gpos = (!(b & 0x8000u)) && (b != 0u);   // g > 0
    if (gpos && kp_) {
      const float tw = bf2f(qpB[i]) * bf2f(kcB[i]) - bf2f(qcB[i]) * bf2f(kpB[i]);
      accv += bf2f(mB[i]) * fabsf(tw);
    }
  }
  #pragma unroll
  for (int off = 1; off < 64; off <<= 1) accv += __shfl_xor(accv, off);
  if (ln == 0) craw[token] = accv * (1.0f / 1024.0f);
}

// ---------------- Phase 3a: quorum sigmoid + codebook shift score ----------------
__global__ __launch_bounds__(256) void quorum_kernel(
    const float* __restrict__ craw, const float* __restrict__ probs,
    float* __restrict__ quorum, float* __restrict__ cb)
{
  const int idx = blockIdx.x * 256 + threadIdx.x;
  const int s = idx & (SS - 1);
  const float c1 = craw[idx];
  const float c0 = (s > 0) ? craw[idx - 1] : 0.f;
  const float c2 = (s < SS - 1) ? craw[idx + 1] : 0.f;
  const float local = (c0 + c1 + c2) / 3.0f;
  quorum[idx] = 1.0f / (1.0f + expf((0.5f - local) * 10.0f));
  float sh = 0.f;
  if (s > 0) {
    #pragma unroll
    for (int j = 0; j < 16; ++j)
      sh += fabsf(probs[(size_t)idx * 16 + j] - probs[(size_t)(idx - 1) * 16 + j]);
  }
  cb[idx] = 0.5f * sh;
}

// ---------------- Phase 3b: per-batch budget top-2048 + final mix ----------------
__global__ __launch_bounds__(64) void final_kernel(
    const float* __restrict__ craw, const float* __restrict__ quorum,
    const float* __restrict__ cb, float* __restrict__ outp)
{
  const int b = blockIdx.x;
  const int ln = threadIdx.x;
  const size_t base = (size_t)b * SS;
  float qv[64]; unsigned int key[64];
  #pragma unroll
  for (int i = 0; i < 64; ++i) {
    qv[i] = quorum[base + ln * 64 + i];
    const unsigned int bb = __float_as_uint(qv[i]);
    key[i] = (bb & 0x80000000u) ? ~bb : (bb | 0x80000000u);
  }
  unsigned int lo = 0u, hi = 0xFFFFFFFFu;
  while (lo < hi) {
    const unsigned int mid = (unsigned int)(((unsigned long long)lo + hi + 1ull) >> 1);
    int c = 0;
    #pragma unroll
    for (int i = 0; i < 64; ++i) c += (key[i] >= mid);
    #pragma unroll
    for (int off = 1; off < 64; off <<= 1) c += __shfl_xor(c, off);
    if (c >= BUDGET) lo = mid; else hi = mid - 1;
  }
  const unsigned int T = lo;
  int cg = 0, myeq = 0;
  #pragma unroll
  for (int i = 0; i < 64; ++i) { cg += (key[i] > T); myeq += (key[i] == T); }
  #pragma unroll
  for (int off = 1; off < 64; off <<= 1) cg += __shfl_xor(cg, off);
  int scan = myeq;
  #pragma unroll
  for (int off = 1; off < 64; off <<= 1) {
    const int nsc = __shfl_up(scan, off);
    if (ln >= off) scan += nsc;
  }
  int ebase = scan - myeq;
  const int keep_eq = BUDGET - cg;
  #pragma unroll
  for (int i = 0; i < 64; ++i) {
    const size_t sidx = base + (size_t)ln * 64 + i;
    const bool kp_ = (key[i] > T) || (key[i] == T && ebase < keep_eq);
    if (key[i] == T) ebase++;
    const float q = kp_ ? qv[i] : 0.f;
    outp[sidx] = 0.7f * (craw[sidx] * (0.5f + 0.5f * q)) + 0.3f * cb[sidx];
  }
}

extern "C" void kernel_launch(void* const* d_in, const int* in_sizes, int n_in,
                              void* d_out, int out_size, void* d_ws, size_t ws_size,
                              hipStream_t stream)
{
  const float* x  = (const float*)d_in[0];
  const float* Wq = (const float*)d_in[1];
  const float* Wk = (const float*)d_in[2];
  const float* Wg = (const float*)d_in[3];
  const float* bg = (const float*)d_in[4];
  const float* Wm = (const float*)d_in[5];
  const float* bm = (const float*)d_in[6];
  const float* Wc = (const float*)d_in[7];
  float* outp = (float*)d_out;
  char* w = (char*)d_ws;

  const size_t SZ_BF = (size_t)MM * DD * 2;        // 32 MB per bf16 intermediate
  const size_t SMALL_OFF = 4 * SZ_BF;              // 134217728
  const size_t SZ_SMALL = 1048576 + 3 * 65536;     // probs + craw/quorum/cb

  unsigned short* qb = (unsigned short*)(w);
  unsigned short* kb = (unsigned short*)(w + SZ_BF);
  unsigned short* gb = (unsigned short*)(w + 2 * SZ_BF);
  unsigned short* mb = (unsigned short*)(w + 3 * SZ_BF);
  char* sm = w + SMALL_OFF;
  float* probs  = (float*)(sm);
  float* craw   = (float*)(sm + 1048576);
  float* quorum = (float*)(sm + 1048576 + 65536);
  float* cbuf   = (float*)(sm + 1048576 + 2 * 65536);

  // mid tier: bf16 copies of x (32MB) + W concat (8MB) after the small buffers
  const size_t need_mid = SMALL_OFF + SZ_SMALL + SZ_BF + (size_t)4 * 1048576 * 2;

  if (ws_size >= need_mid) {
    unsigned short* xb = (unsigned short*)(sm + SZ_SMALL);
    unsigned short* Wb = xb + (size_t)MM * DD;
    convert_kernel<<<2048, 256, 0, stream>>>(x, Wq, Wk, Wg, Wm, xb, Wb);
    mfma_gemm<1, 0><<<dim3(NTOT / 128, MM / 128), 256, 0, stream>>>(
        xb, Wb, x, Wq, Wk, Wg, Wm, bg, bm, qb, kb, gb, mb);
  } else {
    mfma_gemm<0, 0><<<dim3(NTOT / 128, MM / 128), 256, 0, stream>>>(
        nullptr, nullptr, x, Wq, Wk, Wg, Wm, bg, bm, qb, kb, gb, mb);
  }
  token_kernel2<<<dim3(MM / 4), 256, 0, stream>>>(x, Wc, qb, kb, gb, mb, probs, craw);
  quorum_kernel<<<dim3(MM / 256), 256, 0, stream>>>(craw, probs, quorum, cbuf);
  final_kernel<<<dim3(BB), 64, 0, stream>>>(craw, quorum, cbuf, outp);
}

// Round 4
// 296.536 us; speedup vs baseline: 7.0496x; 1.3817x over previous
//
#include <hip/hip_runtime.h>
#include <hip/hip_bf16.h>
#include <cstdint>

// Problem constants
#define BB 4
#define SS 4096
#define DD 1024
#define MM (BB * SS)          // 16384 tokens
#define NTOT 4096             // 4 matrices * 1024 output features
#define BUDGET 2048

typedef __attribute__((ext_vector_type(8))) short short8v;   // 8 bf16 (4 VGPR)
typedef __attribute__((ext_vector_type(4))) float f32x4;

__device__ __forceinline__ float bf2f(unsigned int h) {
  return __uint_as_float(h << 16);
}
__device__ __forceinline__ unsigned short f2bf(float f) {
  unsigned int u = __float_as_uint(f);
  u = u + 0x7FFFu + ((u >> 16) & 1u);   // RNE
  return (unsigned short)(u >> 16);
}
// pack two f32 -> two bf16 (RNE) in one u32 (low = a.x)
__device__ __forceinline__ unsigned int pkbf(float lo, float hi) {
  float2 f; f.x = lo; f.y = hi;
  __hip_bfloat162 h = __float22bfloat162_rn(f);
  return *(unsigned int*)&h;
}

// ---------------- conversion: f32 -> bf16 copies of x and concat(Wq,Wk,Wg,Wm) ----
__global__ __launch_bounds__(256) void convert_kernel(
    const float* __restrict__ x,
    const float* __restrict__ Wq, const float* __restrict__ Wk,
    const float* __restrict__ Wg, const float* __restrict__ Wm,
    unsigned short* __restrict__ xb, unsigned short* __restrict__ Wb)
{
  const size_t NX = (size_t)MM * DD;           // 16777216
  const size_t NCH = (NX + 4u * 1048576u) / 4; // total float4 chunks = 5242880
  size_t i = (size_t)blockIdx.x * 256 + threadIdx.x;
  const size_t stride = (size_t)gridDim.x * 256;
  for (size_t c = i; c < NCH; c += stride) {
    const size_t e = c * 4;
    const float* src; unsigned short* dst;
    if (e < NX) { src = x + e; dst = xb + e; }
    else {
      const size_t w = e - NX;
      const int m = (int)(w >> 20);
      const float* Ws = (m == 0) ? Wq : (m == 1) ? Wk : (m == 2) ? Wg : Wm;
      src = Ws + (w & 1048575u); dst = Wb + w;
    }
    const float4 v = *(const float4*)src;
    uint2 o; o.x = pkbf(v.x, v.y); o.y = pkbf(v.z, v.w);
    *(uint2*)dst = o;
  }
}

// ---------------- 2-phase double-buffered 256x256 MFMA GEMM ----------------
// out[m,n] = sum_k xb[m,k] * Wb[n,k]; BK=32; 8 waves (2M x 4N); per-wave 128x64.
// LDS 64 KB: A[2][256x32], B[2][256x32] bf16. Stage tile t+1 while computing t;
// single __syncthreads per tile provides the vmcnt(0)+lgkmcnt(0) drain + barrier.
__global__ __launch_bounds__(512, 2) void gemm256_kernel(
    const unsigned short* __restrict__ xb, const unsigned short* __restrict__ Wb,
    const float* __restrict__ bg, const float* __restrict__ bm,
    unsigned short* __restrict__ qb, unsigned short* __restrict__ kb,
    unsigned short* __restrict__ gb, unsigned short* __restrict__ mb)
{
  __shared__ __align__(16) unsigned short lds[32768];  // 64 KB
  const int t  = threadIdx.x;
  const int wv = t >> 6, ln = t & 63;
  const int wr = wv >> 2, wc = wv & 3;        // 2 (M) x 4 (N) wave grid
  const int frow = ln & 15, kc = ln >> 4;

  // bijective XCD swizzle: nwg = 16*64 = 1024, 8 XCDs, 128 blocks per XCD chunk
  const int o  = blockIdx.y * 16 + blockIdx.x;
  const int L  = (o & 7) * 128 + (o >> 3);
  const int bx = L & 15, by = L >> 4;
  const int m0 = by * 256;
  const int n0 = bx * 256;
  const int mat = n0 >> 10;
  const int nc0 = n0 & 1023;

  f32x4 acc[8][4];
  #pragma unroll
  for (int i = 0; i < 8; ++i)
    #pragma unroll
    for (int j = 0; j < 4; ++j) { acc[i][j][0]=0.f; acc[i][j][1]=0.f; acc[i][j][2]=0.f; acc[i][j][3]=0.f; }

  // staging: 4 x global_load_lds(16B) per thread per K-tile (A 16KB + B 16KB)
  const int srow = wv * 16 + (ln >> 2);       // source row within 128-row half
  const int scch = (ln & 3) << 3;             // k-chunk of 8 bf16
  auto stage = [&](int buf, int kt) {
    const int k0 = kt << 5;
    #pragma unroll
    for (int i = 0; i < 2; ++i) {
      const unsigned short* ga = xb + (size_t)(m0 + i * 128 + srow) * DD + k0 + scch;
      const unsigned short* gw = Wb + (size_t)(n0 + i * 128 + srow) * DD + k0 + scch;
      __builtin_amdgcn_global_load_lds(
          (const __attribute__((address_space(1))) void*)ga,
          (__attribute__((address_space(3))) void*)((__attribute__((address_space(3))) char*)lds
              + buf * 16384 + i * 8192 + wv * 1024 + ln * 16),
          16, 0, 0);
      __builtin_amdgcn_global_load_lds(
          (const __attribute__((address_space(1))) void*)gw,
          (__attribute__((address_space(3))) void*)((__attribute__((address_space(3))) char*)lds
              + 32768 + buf * 16384 + i * 8192 + wv * 1024 + ln * 16),
          16, 0, 0);
    }
  };

  stage(0, 0);
  __syncthreads();   // drain prologue staging

  for (int kt = 0; kt < 32; ++kt) {
    const int cur = kt & 1;
    if (kt < 31) stage(cur ^ 1, kt + 1);   // loads fly during the MFMAs below

    short8v a[8], b[4];
    #pragma unroll
    for (int j = 0; j < 4; ++j)
      b[j] = *(const short8v*)&lds[16384 + cur * 8192 + (wc * 64 + j * 16 + frow) * 32 + kc * 8];
    #pragma unroll
    for (int i = 0; i < 8; ++i)
      a[i] = *(const short8v*)&lds[cur * 8192 + (wr * 128 + i * 16 + frow) * 32 + kc * 8];

    #pragma unroll
    for (int i = 0; i < 8; ++i)
      #pragma unroll
      for (int j = 0; j < 4; ++j)
        acc[i][j] = __builtin_amdgcn_mfma_f32_16x16x32_bf16(a[i], b[j], acc[i][j], 0, 0, 0);

    __syncthreads();   // one vmcnt(0)+lgkmcnt(0)+barrier per K-tile
  }

  unsigned short* outp = (mat == 0) ? qb : (mat == 1) ? kb : (mat == 2) ? gb : mb;
  #pragma unroll
  for (int i = 0; i < 8; ++i) {
    #pragma unroll
    for (int j = 0; j < 4; ++j) {
      const int col = nc0 + wc * 64 + j * 16 + frow;
      const float bias = (mat == 2) ? bg[col] : (mat == 3) ? bm[col] : 0.f;
      #pragma unroll
      for (int r = 0; r < 4; ++r) {
        const int row = m0 + wr * 128 + i * 16 + kc * 4 + r;
        float v = acc[i][j][r] + bias;
        if (mat == 3) v = fmaxf(v, 0.0f);
        outp[(size_t)row * DD + col] = f2bf(v);
      }
    }
  }
}

// ---------------- fallback GEMM (ws too small): reg-staged f32->bf16, 128x128 ----
__global__ __launch_bounds__(256) void mfma_gemm_fb(
    const float* __restrict__ x,
    const float* __restrict__ Wq, const float* __restrict__ Wk,
    const float* __restrict__ Wg, const float* __restrict__ Wm,
    const float* __restrict__ bg, const float* __restrict__ bm,
    unsigned short* __restrict__ q_o, unsigned short* __restrict__ k_o,
    unsigned short* __restrict__ g_o, unsigned short* __restrict__ m_o)
{
  __shared__ __align__(16) unsigned short As[128 * 32];
  __shared__ __align__(16) unsigned short Bs[128 * 32];
  const int t  = threadIdx.x;
  const int wv = t >> 6, ln = t & 63;
  const int wr = wv >> 1, wc = wv & 1;
  const int m0 = blockIdx.y * 128;
  const int n0 = blockIdx.x * 128;
  const int mat = n0 >> 10;
  const int nc0 = n0 & 1023;
  const float* __restrict__ Wsrc = (mat == 0) ? Wq : (mat == 1) ? Wk : (mat == 2) ? Wg : Wm;

  f32x4 acc[4][4];
  #pragma unroll
  for (int i = 0; i < 4; ++i)
    #pragma unroll
    for (int j = 0; j < 4; ++j) { acc[i][j][0]=0.f; acc[i][j][1]=0.f; acc[i][j][2]=0.f; acc[i][j][3]=0.f; }

  const int frow = ln & 15, kc = ln >> 4;

  for (int k0 = 0; k0 < DD; k0 += 32) {
    #pragma unroll
    for (int c = 0; c < 2; ++c) {
      const int i = c * 256 + t;
      const int row = i >> 2, colc = i & 3;
      const float* ga = x    + (size_t)(m0 + row) * DD + k0 + (colc << 3);
      const float* gw = Wsrc + (size_t)(nc0 + row) * DD + k0 + (colc << 3);
      const float4 a0 = *(const float4*)ga, a1 = *(const float4*)(ga + 4);
      const float4 b0 = *(const float4*)gw, b1 = *(const float4*)(gw + 4);
      uint4 ao, bo;
      ao.x = pkbf(a0.x, a0.y); ao.y = pkbf(a0.z, a0.w);
      ao.z = pkbf(a1.x, a1.y); ao.w = pkbf(a1.z, a1.w);
      bo.x = pkbf(b0.x, b0.y); bo.y = pkbf(b0.z, b0.w);
      bo.z = pkbf(b1.x, b1.y); bo.w = pkbf(b1.z, b1.w);
      *(uint4*)&As[row * 32 + colc * 8] = ao;
      *(uint4*)&Bs[row * 32 + colc * 8] = bo;
    }
    __syncthreads();
    short8v a[4], b[4];
    #pragma unroll
    for (int i = 0; i < 4; ++i) {
      a[i] = *(const short8v*)&As[(wr * 64 + i * 16 + frow) * 32 + kc * 8];
      b[i] = *(const short8v*)&Bs[(wc * 64 + i * 16 + frow) * 32 + kc * 8];
    }
    #pragma unroll
    for (int i = 0; i < 4; ++i)
      #pragma unroll
      for (int j = 0; j < 4; ++j)
        acc[i][j] = __builtin_amdgcn_mfma_f32_16x16x32_bf16(a[i], b[j], acc[i][j], 0, 0, 0);
    __syncthreads();
  }

  unsigned short* outp = (mat == 0) ? q_o : (mat == 1) ? k_o : (mat == 2) ? g_o : m_o;
  #pragma unroll
  for (int i = 0; i < 4; ++i) {
    #pragma unroll
    for (int j = 0; j < 4; ++j) {
      const int col = nc0 + wc * 64 + j * 16 + frow;
      #pragma unroll
      for (int r = 0; r < 4; ++r) {
        const int row = m0 + wr * 64 + i * 16 + kc * 4 + r;
        float v = acc[i][j][r];
        if (mat == 2) v += bg[col];
        if (mat == 3) v = fmaxf(v + bm[col], 0.0f);
        outp[(size_t)row * DD + col] = f2bf(v);
      }
    }
  }
}

// ---------------- Phase 2: wave-per-token, zero barriers ----------------
__global__ __launch_bounds__(256) void token_kernel2(
    const float* __restrict__ x, const float* __restrict__ Wc,
    const unsigned short* __restrict__ qb, const unsigned short* __restrict__ kb,
    const unsigned short* __restrict__ gb, const unsigned short* __restrict__ mb,
    float* __restrict__ probs, float* __restrict__ craw)
{
  const int wv = threadIdx.x >> 6;
  const int ln = threadIdx.x & 63;
  const int token = blockIdx.x * 4 + wv;
  const int s = token & (SS - 1);
  const size_t rowo = (size_t)token * DD;

  // --- codebook logits: per-lane partials over disjoint d, butterfly reduce ---
  const float4* x4 = (const float4*)(x + rowo);
  const float4* Wc4 = (const float4*)Wc;
  float4 xv[4];
  #pragma unroll
  for (int e = 0; e < 4; ++e) xv[e] = x4[e * 64 + ln];
  float pj[16];
  #pragma unroll
  for (int j = 0; j < 16; ++j) {
    float a = 0.f;
    #pragma unroll
    for (int e = 0; e < 4; ++e) {
      const float4 w = Wc4[j * 256 + e * 64 + ln];
      a += xv[e].x * w.x + xv[e].y * w.y + xv[e].z * w.z + xv[e].w * w.w;
    }
    pj[j] = a;
  }
  #pragma unroll
  for (int j = 0; j < 16; ++j) {
    #pragma unroll
    for (int off = 1; off < 64; off <<= 1) pj[j] += __shfl_xor(pj[j], off);
  }
  if (ln == 0) {
    float p[16];
    float mx = -3.4e38f;
    #pragma unroll
    for (int j = 0; j < 16; ++j) { p[j] = pj[j] * 10.0f; mx = fmaxf(mx, p[j]); }
    float se = 0.f;
    #pragma unroll
    for (int j = 0; j < 16; ++j) { p[j] = expf(p[j] - mx); se += p[j]; }
    const float inv = 1.0f / se;
    #pragma unroll
    for (int j = 0; j < 16; ++j) p[j] *= inv;
    unsigned int mk = 0;
    for (int it = 0; it < 4; ++it) {
      int bi = 0; float bv = -1.f;
      #pragma unroll
      for (int j = 0; j < 16; ++j)
        if (!((mk >> j) & 1u) && p[j] > bv) { bv = p[j]; bi = j; }
      mk |= 1u << bi;
    }
    float ssum = 0.f;
    #pragma unroll
    for (int j = 0; j < 16; ++j) if ((mk >> j) & 1u) ssum += p[j];
    const float rinv = 1.0f / fmaxf(ssum, 1e-8f);
    #pragma unroll
    for (int j = 0; j < 16; ++j)
      probs[(size_t)token * 16 + j] = ((mk >> j) & 1u) ? p[j] * rinv : 0.f;
  }

  if (s == 0) { if (ln == 0) craw[token] = 0.f; return; }

  // --- adaptive top-k gate: 16-bit keys from bf16 bits ---
  unsigned short gbit[16];
  *(uint4*)&gbit[0] = *(const uint4*)(gb + rowo + ln * 16);
  *(uint4*)&gbit[8] = *(const uint4*)(gb + rowo + ln * 16 + 8);
  int ckey[16];
  float asum = 0.f;
  #pragma unroll
  for (int i = 0; i < 16; ++i) {
    const unsigned int b = gbit[i];
    ckey[i] = (b & 0x8000u) ? (int)(b ^ 0xFFFFu) : (int)(b | 0x8000u);
    asum += bf2f(b & 0x7FFFu);
  }
  #pragma unroll
  for (int off = 1; off < 64; off <<= 1) asum += __shfl_xor(asum, off);
  const float strength = tanhf(asum * (1.0f / 1024.0f));
  int kkv = (int)ceilf(strength * 256.0f);
  kkv = min(max(kkv, 1), 1024);

  int lo = 0, hi = 0xFFFF;
  while (lo < hi) {
    const int mid = (lo + hi + 1) >> 1;
    int c = 0;
    #pragma unroll
    for (int i = 0; i < 16; ++i) c += (ckey[i] >= mid);
    #pragma unroll
    for (int off = 1; off < 64; off <<= 1) c += __shfl_xor(c, off);
    if (c >= kkv) lo = mid; else hi = mid - 1;
  }
  const int T = lo;

  int cg = 0, myeq = 0;
  #pragma unroll
  for (int i = 0; i < 16; ++i) { cg += (ckey[i] > T); myeq += (ckey[i] == T); }
  #pragma unroll
  for (int off = 1; off < 64; off <<= 1) cg += __shfl_xor(cg, off);
  int incl = myeq;
  #pragma unroll
  for (int off = 1; off < 64; off <<= 1) {
    const int tt = __shfl_up(incl, off);
    if (ln >= off) incl += tt;
  }
  int ebase = incl - myeq;
  const int keep_eq = kkv - cg;

  unsigned short mB[16], qcB[16], kcB[16], qpB[16], kpB[16];
  *(uint4*)&mB[0]  = *(const uint4*)(mb + rowo + ln * 16);
  *(uint4*)&mB[8]  = *(const uint4*)(mb + rowo + ln * 16 + 8);
  *(uint4*)&qcB[0] = *(const uint4*)(qb + rowo + ln * 16);
  *(uint4*)&qcB[8] = *(const uint4*)(qb + rowo + ln * 16 + 8);
  *(uint4*)&kcB[0] = *(const uint4*)(kb + rowo + ln * 16);
  *(uint4*)&kcB[8] = *(const uint4*)(kb + rowo + ln * 16 + 8);
  *(uint4*)&qpB[0] = *(const uint4*)(qb + rowo - DD + ln * 16);
  *(uint4*)&qpB[8] = *(const uint4*)(qb + rowo - DD + ln * 16 + 8);
  *(uint4*)&kpB[0] = *(const uint4*)(kb + rowo - DD + ln * 16);
  *(uint4*)&kpB[8] = *(const uint4*)(kb + rowo - DD + ln * 16 + 8);

  float accv = 0.f;
  #pragma unroll
  for (int i = 0; i < 16; ++i) {
    const bool kp_ = (ckey[i] > T) || (ckey[i] == T && ebase < keep_eq);
    if (ckey[i] == T) ebase++;
    const unsigned int b = gbit[i];
    const bool gpos = (!(b & 0x8000u)) && (b != 0u);   // g > 0
    if (gpos && kp_) {
      const float tw = bf2f(qpB[i]) * bf2f(kcB[i]) - bf2f(qcB[i]) * bf2f(kpB[i]);
      accv += bf2f(mB[i]) * fabsf(tw);
    }
  }
  #pragma unroll
  for (int off = 1; off < 64; off <<= 1) accv += __shfl_xor(accv, off);
  if (ln == 0) craw[token] = accv * (1.0f / 1024.0f);
}

// ---------------- Phase 3a: quorum sigmoid + codebook shift score ----------------
__global__ __launch_bounds__(256) void quorum_kernel(
    const float* __restrict__ craw, const float* __restrict__ probs,
    float* __restrict__ quorum, float* __restrict__ cb)
{
  const int idx = blockIdx.x * 256 + threadIdx.x;
  const int s = idx & (SS - 1);
  const float c1 = craw[idx];
  const float c0 = (s > 0) ? craw[idx - 1] : 0.f;
  const float c2 = (s < SS - 1) ? craw[idx + 1] : 0.f;
  const float local = (c0 + c1 + c2) / 3.0f;
  quorum[idx] = 1.0f / (1.0f + expf((0.5f - local) * 10.0f));
  float sh = 0.f;
  if (s > 0) {
    #pragma unroll
    for (int j = 0; j < 16; ++j)
      sh += fabsf(probs[(size_t)idx * 16 + j] - probs[(size_t)(idx - 1) * 16 + j]);
  }
  cb[idx] = 0.5f * sh;
}

// ---------------- Phase 3b: per-batch budget top-2048 + final mix ----------------
__global__ __launch_bounds__(64) void final_kernel(
    const float* __restrict__ craw, const float* __restrict__ quorum,
    const float* __restrict__ cb, float* __restrict__ outp)
{
  const int b = blockIdx.x;
  const int ln = threadIdx.x;
  const size_t base = (size_t)b * SS;
  float qv[64]; unsigned int key[64];
  #pragma unroll
  for (int i = 0; i < 64; ++i) {
    qv[i] = quorum[base + ln * 64 + i];
    const unsigned int bb = __float_as_uint(qv[i]);
    key[i] = (bb & 0x80000000u) ? ~bb : (bb | 0x80000000u);
  }
  unsigned int lo = 0u, hi = 0xFFFFFFFFu;
  while (lo < hi) {
    const unsigned int mid = (unsigned int)(((unsigned long long)lo + hi + 1ull) >> 1);
    int c = 0;
    #pragma unroll
    for (int i = 0; i < 64; ++i) c += (key[i] >= mid);
    #pragma unroll
    for (int off = 1; off < 64; off <<= 1) c += __shfl_xor(c, off);
    if (c >= BUDGET) lo = mid; else hi = mid - 1;
  }
  const unsigned int T = lo;
  int cg = 0, myeq = 0;
  #pragma unroll
  for (int i = 0; i < 64; ++i) { cg += (key[i] > T); myeq += (key[i] == T); }
  #pragma unroll
  for (int off = 1; off < 64; off <<= 1) cg += __shfl_xor(cg, off);
  int scan = myeq;
  #pragma unroll
  for (int off = 1; off < 64; off <<= 1) {
    const int nsc = __shfl_up(scan, off);
    if (ln >= off) scan += nsc;
  }
  int ebase = scan - myeq;
  const int keep_eq = BUDGET - cg;
  #pragma unroll
  for (int i = 0; i < 64; ++i) {
    const size_t sidx = base + (size_t)ln * 64 + i;
    const bool kp_ = (key[i] > T) || (key[i] == T && ebase < keep_eq);
    if (key[i] == T) ebase++;
    const float q = kp_ ? qv[i] : 0.f;
    outp[sidx] = 0.7f * (craw[sidx] * (0.5f + 0.5f * q)) + 0.3f * cb[sidx];
  }
}

extern "C" void kernel_launch(void* const* d_in, const int* in_sizes, int n_in,
                              void* d_out, int out_size, void* d_ws, size_t ws_size,
                              hipStream_t stream)
{
  const float* x  = (const float*)d_in[0];
  const float* Wq = (const float*)d_in[1];
  const float* Wk = (const float*)d_in[2];
  const float* Wg = (const float*)d_in[3];
  const float* bg = (const float*)d_in[4];
  const float* Wm = (const float*)d_in[5];
  const float* bm = (const float*)d_in[6];
  const float* Wc = (const float*)d_in[7];
  float* outp = (float*)d_out;
  char* w = (char*)d_ws;

  const size_t SZ_BF = (size_t)MM * DD * 2;        // 32 MB per bf16 intermediate
  const size_t SMALL_OFF = 4 * SZ_BF;              // 134217728
  const size_t SZ_SMALL = 1048576 + 3 * 65536;     // probs + craw/quorum/cb

  unsigned short* qb = (unsigned short*)(w);
  unsigned short* kb = (unsigned short*)(w + SZ_BF);
  unsigned short* gb = (unsigned short*)(w + 2 * SZ_BF);
  unsigned short* mb = (unsigned short*)(w + 3 * SZ_BF);
  char* sm = w + SMALL_OFF;
  float* probs  = (float*)(sm);
  float* craw   = (float*)(sm + 1048576);
  float* quorum = (float*)(sm + 1048576 + 65536);
  float* cbuf   = (float*)(sm + 1048576 + 2 * 65536);

  const size_t need_mid = SMALL_OFF + SZ_SMALL + SZ_BF + (size_t)4 * 1048576 * 2;

  if (ws_size >= need_mid) {
    unsigned short* xb = (unsigned short*)(sm + SZ_SMALL);
    unsigned short* Wb = xb + (size_t)MM * DD;
    convert_kernel<<<2048, 256, 0, stream>>>(x, Wq, Wk, Wg, Wm, xb, Wb);
    gemm256_kernel<<<dim3(NTOT / 256, MM / 256), 512, 0, stream>>>(
        xb, Wb, bg, bm, qb, kb, gb, mb);
  } else {
    mfma_gemm_fb<<<dim3(NTOT / 128, MM / 128), 256, 0, stream>>>(
        x, Wq, Wk, Wg, Wm, bg, bm, qb, kb, gb, mb);
  }
  token_kernel2<<<dim3(MM / 4), 256, 0, stream>>>(x, Wc, qb, kb, gb, mb, probs, craw);
  quorum_kernel<<<dim3(MM / 256), 256, 0, stream>>>(craw, probs, quorum, cbuf);
  final_kernel<<<dim3(BB), 64, 0, stream>>>(craw, quorum, cbuf, outp);
}

// Round 5
// 286.477 us; speedup vs baseline: 7.2971x; 1.0351x over previous
//
#include <hip/hip_runtime.h>
#include <hip/hip_bf16.h>
#include <cstdint>

// Problem constants
#define BB 4
#define SS 4096
#define DD 1024
#define MM (BB * SS)          // 16384 tokens
#define NTOT 4096             // 4 matrices * 1024 output features
#define BUDGET 2048

typedef __attribute__((ext_vector_type(8))) short short8v;   // 8 bf16 (4 VGPR)
typedef __attribute__((ext_vector_type(4))) float f32x4;

__device__ __forceinline__ float bf2f(unsigned int h) {
  return __uint_as_float(h << 16);
}
__device__ __forceinline__ unsigned short f2bf(float f) {
  unsigned int u = __float_as_uint(f);
  u = u + 0x7FFFu + ((u >> 16) & 1u);   // RNE
  return (unsigned short)(u >> 16);
}
__device__ __forceinline__ unsigned int pkbf(float lo, float hi) {
  float2 f; f.x = lo; f.y = hi;
  __hip_bfloat162 h = __float22bfloat162_rn(f);
  return *(unsigned int*)&h;
}

// ---------------- convert2: bf16 copies of x & W-concat + fused codebook probs ----
// Blocks [0,4096): wave-per-token — convert x row, compute codebook logits (f32 x,
// exact), softmax + top-4 renorm -> probs. Blocks [4096, 6144): W conversion.
__global__ __launch_bounds__(256) void convert2_kernel(
    const float* __restrict__ x,
    const float* __restrict__ Wq, const float* __restrict__ Wk,
    const float* __restrict__ Wg, const float* __restrict__ Wm,
    const float* __restrict__ Wc,
    unsigned short* __restrict__ xb, unsigned short* __restrict__ Wb,
    float* __restrict__ probs)
{
  const int blk = blockIdx.x;
  const int t = threadIdx.x;
  if (blk < 4096) {
    const int wv = t >> 6, ln = t & 63;
    const int token = blk * 4 + wv;
    const size_t rowo = (size_t)token * DD;
    const float4* x4 = (const float4*)(x + rowo);
    const float4* Wc4 = (const float4*)Wc;
    float4 xv[4];
    #pragma unroll
    for (int e = 0; e < 4; ++e) xv[e] = x4[e * 64 + ln];
    uint2* xo = (uint2*)(xb + rowo);
    #pragma unroll
    for (int e = 0; e < 4; ++e) {
      uint2 o; o.x = pkbf(xv[e].x, xv[e].y); o.y = pkbf(xv[e].z, xv[e].w);
      xo[e * 64 + ln] = o;
    }
    float pj[16];
    #pragma unroll
    for (int j = 0; j < 16; ++j) {
      float a = 0.f;
      #pragma unroll
      for (int e = 0; e < 4; ++e) {
        const float4 w = Wc4[j * 256 + e * 64 + ln];
        a += xv[e].x * w.x + xv[e].y * w.y + xv[e].z * w.z + xv[e].w * w.w;
      }
      pj[j] = a;
    }
    #pragma unroll
    for (int j = 0; j < 16; ++j) {
      #pragma unroll
      for (int off = 1; off < 64; off <<= 1) pj[j] += __shfl_xor(pj[j], off);
    }
    if (ln == 0) {
      float p[16];
      float mx = -3.4e38f;
      #pragma unroll
      for (int j = 0; j < 16; ++j) { p[j] = pj[j] * 10.0f; mx = fmaxf(mx, p[j]); }
      float se = 0.f;
      #pragma unroll
      for (int j = 0; j < 16; ++j) { p[j] = expf(p[j] - mx); se += p[j]; }
      const float inv = 1.0f / se;
      #pragma unroll
      for (int j = 0; j < 16; ++j) p[j] *= inv;
      unsigned int mk = 0;
      for (int it = 0; it < 4; ++it) {
        int bi = 0; float bv = -1.f;
        #pragma unroll
        for (int j = 0; j < 16; ++j)
          if (!((mk >> j) & 1u) && p[j] > bv) { bv = p[j]; bi = j; }
        mk |= 1u << bi;
      }
      float ssum = 0.f;
      #pragma unroll
      for (int j = 0; j < 16; ++j) if ((mk >> j) & 1u) ssum += p[j];
      const float rinv = 1.0f / fmaxf(ssum, 1e-8f);
      #pragma unroll
      for (int j = 0; j < 16; ++j)
        probs[(size_t)token * 16 + j] = ((mk >> j) & 1u) ? p[j] * rinv : 0.f;
    }
  } else {
    // W part: 2048 blocks x 2048 floats; thread -> 8 consecutive floats
    const size_t off0 = (size_t)(blk - 4096) * 2048 + t * 8;
    const int m = (int)(off0 >> 20);
    const float* Ws = (m == 0) ? Wq : (m == 1) ? Wk : (m == 2) ? Wg : Wm;
    const size_t wo = off0 & 1048575u;
    const float4 a0 = *(const float4*)(Ws + wo);
    const float4 a1 = *(const float4*)(Ws + wo + 4);
    uint4 o;
    o.x = pkbf(a0.x, a0.y); o.y = pkbf(a0.z, a0.w);
    o.z = pkbf(a1.x, a1.y); o.w = pkbf(a1.z, a1.w);
    *(uint4*)(Wb + off0) = o;
  }
}

// ---------------- 2-buffer counted-vmcnt 256x256 MFMA GEMM ----------------
// out[m,n] = sum_k xb[m,k]*Wb[n,k]; BK=32; 8 waves (2Mx4N); per-wave 128x64.
// Raw s_barrier + s_waitcnt vmcnt(4): next tile's 4 loads stay in flight across
// both barriers (T4). LDS k-chunk XOR swizzle (slot ^= row&3) applied on the
// GLOBAL source + the ds_read side (linear gload_lds dest) -> 8-way bank
// conflict becomes 2-way.
__global__ __launch_bounds__(512, 2) void gemm256_kernel(
    const unsigned short* __restrict__ xb, const unsigned short* __restrict__ Wb,
    const float* __restrict__ bg, const float* __restrict__ bm,
    unsigned short* __restrict__ qb, unsigned short* __restrict__ kb,
    unsigned short* __restrict__ gb, unsigned short* __restrict__ mb)
{
  __shared__ __align__(16) unsigned short lds[32768];  // 64 KB: A[2][8K], B[2][8K] ushorts
  const int t  = threadIdx.x;
  const int wv = t >> 6, ln = t & 63;
  const int wr = wv >> 2, wc = wv & 3;        // 2 (M) x 4 (N) wave grid
  const int frow = ln & 15, kc = ln >> 4;

  // bijective XCD swizzle: nwg = 1024, 8 XCDs, 128 blocks per chunk
  const int o  = blockIdx.y * 16 + blockIdx.x;
  const int L  = (o & 7) * 128 + (o >> 3);
  const int bx = L & 15, by = L >> 4;
  const int m0 = by * 256;
  const int n0 = bx * 256;
  const int mat = n0 >> 10;
  const int nc0 = n0 & 1023;

  f32x4 acc[8][4];
  #pragma unroll
  for (int i = 0; i < 8; ++i)
    #pragma unroll
    for (int j = 0; j < 4; ++j) { acc[i][j][0]=0.f; acc[i][j][1]=0.f; acc[i][j][2]=0.f; acc[i][j][3]=0.f; }

  const int srow = wv * 16 + (ln >> 2);                      // row within 128-half
  const int scch = (((ln & 3) ^ ((ln >> 2) & 3)) << 3);      // swizzled source k-chunk
  auto stage = [&](int buf, int kt) {
    const int k0 = kt << 5;
    #pragma unroll
    for (int i = 0; i < 2; ++i) {
      const unsigned short* ga = xb + (size_t)(m0 + i * 128 + srow) * DD + k0 + scch;
      const unsigned short* gw = Wb + (size_t)(n0 + i * 128 + srow) * DD + k0 + scch;
      __builtin_amdgcn_global_load_lds(
          (const __attribute__((address_space(1))) void*)ga,
          (__attribute__((address_space(3))) void*)((__attribute__((address_space(3))) char*)lds
              + buf * 16384 + i * 8192 + wv * 1024 + ln * 16),
          16, 0, 0);
      __builtin_amdgcn_global_load_lds(
          (const __attribute__((address_space(1))) void*)gw,
          (__attribute__((address_space(3))) void*)((__attribute__((address_space(3))) char*)lds
              + 32768 + buf * 16384 + i * 8192 + wv * 1024 + ln * 16),
          16, 0, 0);
    }
  };

  stage(0, 0);
  const int sl = ((kc ^ (frow & 3)) << 3);   // swizzled read slot (ushorts)

  for (int kt = 0; kt < 32; ++kt) {
    const int cur = kt & 1;
    if (kt < 31) {
      stage(cur ^ 1, kt + 1);                              // 8 outstanding
      asm volatile("s_waitcnt vmcnt(4)" ::: "memory");     // tile kt's 4 done
    } else {
      asm volatile("s_waitcnt vmcnt(0)" ::: "memory");
    }
    __builtin_amdgcn_s_barrier();                          // all threads: tile in LDS
    asm volatile("" ::: "memory");

    short8v a[8], b[4];
    #pragma unroll
    for (int j = 0; j < 4; ++j)
      b[j] = *(const short8v*)&lds[16384 + cur * 8192 + (wc * 64 + j * 16 + frow) * 32 + sl];
    #pragma unroll
    for (int i = 0; i < 8; ++i)
      a[i] = *(const short8v*)&lds[cur * 8192 + (wr * 128 + i * 16 + frow) * 32 + sl];

    #pragma unroll
    for (int i = 0; i < 8; ++i)
      #pragma unroll
      for (int j = 0; j < 4; ++j)
        acc[i][j] = __builtin_amdgcn_mfma_f32_16x16x32_bf16(a[i], b[j], acc[i][j], 0, 0, 0);

    asm volatile("" ::: "memory");                         // pin ds_reads above
    __builtin_amdgcn_s_barrier();                          // done reading buf[cur]
  }

  unsigned short* outp = (mat == 0) ? qb : (mat == 1) ? kb : (mat == 2) ? gb : mb;
  #pragma unroll
  for (int i = 0; i < 8; ++i) {
    #pragma unroll
    for (int j = 0; j < 4; ++j) {
      const int col = nc0 + wc * 64 + j * 16 + frow;
      const float bias = (mat == 2) ? bg[col] : (mat == 3) ? bm[col] : 0.f;
      #pragma unroll
      for (int r = 0; r < 4; ++r) {
        const int row = m0 + wr * 128 + i * 16 + kc * 4 + r;
        float v = acc[i][j][r] + bias;
        if (mat == 3) v = fmaxf(v, 0.0f);
        outp[(size_t)row * DD + col] = f2bf(v);
      }
    }
  }
}

// ---------------- fallback GEMM (ws too small): reg-staged f32->bf16, 128x128 ----
__global__ __launch_bounds__(256) void mfma_gemm_fb(
    const float* __restrict__ x,
    const float* __restrict__ Wq, const float* __restrict__ Wk,
    const float* __restrict__ Wg, const float* __restrict__ Wm,
    const float* __restrict__ bg, const float* __restrict__ bm,
    unsigned short* __restrict__ q_o, unsigned short* __restrict__ k_o,
    unsigned short* __restrict__ g_o, unsigned short* __restrict__ m_o)
{
  __shared__ __align__(16) unsigned short As[128 * 32];
  __shared__ __align__(16) unsigned short Bs[128 * 32];
  const int t  = threadIdx.x;
  const int wv = t >> 6, ln = t & 63;
  const int wr = wv >> 1, wc = wv & 1;
  const int m0 = blockIdx.y * 128;
  const int n0 = blockIdx.x * 128;
  const int mat = n0 >> 10;
  const int nc0 = n0 & 1023;
  const float* __restrict__ Wsrc = (mat == 0) ? Wq : (mat == 1) ? Wk : (mat == 2) ? Wg : Wm;

  f32x4 acc[4][4];
  #pragma unroll
  for (int i = 0; i < 4; ++i)
    #pragma unroll
    for (int j = 0; j < 4; ++j) { acc[i][j][0]=0.f; acc[i][j][1]=0.f; acc[i][j][2]=0.f; acc[i][j][3]=0.f; }

  const int frow = ln & 15, kc = ln >> 4;

  for (int k0 = 0; k0 < DD; k0 += 32) {
    #pragma unroll
    for (int c = 0; c < 2; ++c) {
      const int i = c * 256 + t;
      const int row = i >> 2, colc = i & 3;
      const float* ga = x    + (size_t)(m0 + row) * DD + k0 + (colc << 3);
      const float* gw = Wsrc + (size_t)(nc0 + row) * DD + k0 + (colc << 3);
      const float4 a0 = *(const float4*)ga, a1 = *(const float4*)(ga + 4);
      const float4 b0 = *(const float4*)gw, b1 = *(const float4*)(gw + 4);
      uint4 ao, bo;
      ao.x = pkbf(a0.x, a0.y); ao.y = pkbf(a0.z, a0.w);
      ao.z = pkbf(a1.x, a1.y); ao.w = pkbf(a1.z, a1.w);
      bo.x = pkbf(b0.x, b0.y); bo.y = pkbf(b0.z, b0.w);
      bo.z = pkbf(b1.x, b1.y); bo.w = pkbf(b1.z, b1.w);
      *(uint4*)&As[row * 32 + colc * 8] = ao;
      *(uint4*)&Bs[row * 32 + colc * 8] = bo;
    }
    __syncthreads();
    short8v a[4], b[4];
    #pragma unroll
    for (int i = 0; i < 4; ++i) {
      a[i] = *(const short8v*)&As[(wr * 64 + i * 16 + frow) * 32 + kc * 8];
      b[i] = *(const short8v*)&Bs[(wc * 64 + i * 16 + frow) * 32 + kc * 8];
    }
    #pragma unroll
    for (int i = 0; i < 4; ++i)
      #pragma unroll
      for (int j = 0; j < 4; ++j)
        acc[i][j] = __builtin_amdgcn_mfma_f32_16x16x32_bf16(a[i], b[j], acc[i][j], 0, 0, 0);
    __syncthreads();
  }

  unsigned short* outp = (mat == 0) ? q_o : (mat == 1) ? k_o : (mat == 2) ? g_o : m_o;
  #pragma unroll
  for (int i = 0; i < 4; ++i) {
    #pragma unroll
    for (int j = 0; j < 4; ++j) {
      const int col = nc0 + wc * 64 + j * 16 + frow;
      #pragma unroll
      for (int r = 0; r < 4; ++r) {
        const int row = m0 + wr * 64 + i * 16 + kc * 4 + r;
        float v = acc[i][j][r];
        if (mat == 2) v += bg[col];
        if (mat == 3) v = fmaxf(v + bm[col], 0.0f);
        outp[(size_t)row * DD + col] = f2bf(v);
      }
    }
  }
}

// ---------------- Phase 2 (slim): wave-per-token gate/topk/twist only ----------------
__global__ __launch_bounds__(256) void token_kernel3(
    const unsigned short* __restrict__ qb, const unsigned short* __restrict__ kb,
    const unsigned short* __restrict__ gb, const unsigned short* __restrict__ mb,
    float* __restrict__ craw)
{
  const int wv = threadIdx.x >> 6;
  const int ln = threadIdx.x & 63;
  const int token = blockIdx.x * 4 + wv;
  const int s = token & (SS - 1);
  const size_t rowo = (size_t)token * DD;

  if (s == 0) { if (ln == 0) craw[token] = 0.f; return; }

  unsigned short gbit[16];
  *(uint4*)&gbit[0] = *(const uint4*)(gb + rowo + ln * 16);
  *(uint4*)&gbit[8] = *(const uint4*)(gb + rowo + ln * 16 + 8);
  int ckey[16];
  float asum = 0.f;
  #pragma unroll
  for (int i = 0; i < 16; ++i) {
    const unsigned int b = gbit[i];
    ckey[i] = (b & 0x8000u) ? (int)(b ^ 0xFFFFu) : (int)(b | 0x8000u);
    asum += bf2f(b & 0x7FFFu);
  }
  #pragma unroll
  for (int off = 1; off < 64; off <<= 1) asum += __shfl_xor(asum, off);
  const float strength = tanhf(asum * (1.0f / 1024.0f));
  int kkv = (int)ceilf(strength * 256.0f);
  kkv = min(max(kkv, 1), 1024);

  int lo = 0, hi = 0xFFFF;
  while (lo < hi) {
    const int mid = (lo + hi + 1) >> 1;
    int c = 0;
    #pragma unroll
    for (int i = 0; i < 16; ++i) c += (ckey[i] >= mid);
    #pragma unroll
    for (int off = 1; off < 64; off <<= 1) c += __shfl_xor(c, off);
    if (c >= kkv) lo = mid; else hi = mid - 1;
  }
  const int T = lo;

  int cg = 0, myeq = 0;
  #pragma unroll
  for (int i = 0; i < 16; ++i) { cg += (ckey[i] > T); myeq += (ckey[i] == T); }
  #pragma unroll
  for (int off = 1; off < 64; off <<= 1) cg += __shfl_xor(cg, off);
  int incl = myeq;
  #pragma unroll
  for (int off = 1; off < 64; off <<= 1) {
    const int tt = __shfl_up(incl, off);
    if (ln >= off) incl += tt;
  }
  int ebase = incl - myeq;
  const int keep_eq = kkv - cg;

  unsigned short mB[16], qcB[16], kcB[16], qpB[16], kpB[16];
  *(uint4*)&mB[0]  = *(const uint4*)(mb + rowo + ln * 16);
  *(uint4*)&mB[8]  = *(const uint4*)(mb + rowo + ln * 16 + 8);
  *(uint4*)&qcB[0] = *(const uint4*)(qb + rowo + ln * 16);
  *(uint4*)&qcB[8] = *(const uint4*)(qb + rowo + ln * 16 + 8);
  *(uint4*)&kcB[0] = *(const uint4*)(kb + rowo + ln * 16);
  *(uint4*)&kcB[8] = *(const uint4*)(kb + rowo + ln * 16 + 8);
  *(uint4*)&qpB[0] = *(const uint4*)(qb + rowo - DD + ln * 16);
  *(uint4*)&qpB[8] = *(const uint4*)(qb + rowo - DD + ln * 16 + 8);
  *(uint4*)&kpB[0] = *(const uint4*)(kb + rowo - DD + ln * 16);
  *(uint4*)&kpB[8] = *(const uint4*)(kb + rowo - DD + ln * 16 + 8);

  float accv = 0.f;
  #pragma unroll
  for (int i = 0; i < 16; ++i) {
    const bool kp_ = (ckey[i] > T) || (ckey[i] == T && ebase < keep_eq);
    if (ckey[i] == T) ebase++;
    const unsigned int b = gbit[i];
    const bool gpos = (!(b & 0x8000u)) && (b != 0u);   // g > 0
    if (gpos && kp_) {
      const float tw = bf2f(qpB[i]) * bf2f(kcB[i]) - bf2f(qcB[i]) * bf2f(kpB[i]);
      accv += bf2f(mB[i]) * fabsf(tw);
    }
  }
  #pragma unroll
  for (int off = 1; off < 64; off <<= 1) accv += __shfl_xor(accv, off);
  if (ln == 0) craw[token] = accv * (1.0f / 1024.0f);
}

// ---------------- full token kernel (fallback path only) ----------------
__global__ __launch_bounds__(256) void token_kernel2(
    const float* __restrict__ x, const float* __restrict__ Wc,
    const unsigned short* __restrict__ qb, const unsigned short* __restrict__ kb,
    const unsigned short* __restrict__ gb, const unsigned short* __restrict__ mb,
    float* __restrict__ probs, float* __restrict__ craw)
{
  const int wv = threadIdx.x >> 6;
  const int ln = threadIdx.x & 63;
  const int token = blockIdx.x * 4 + wv;
  const int s = token & (SS - 1);
  const size_t rowo = (size_t)token * DD;

  const float4* x4 = (const float4*)(x + rowo);
  const float4* Wc4 = (const float4*)Wc;
  float4 xv[4];
  #pragma unroll
  for (int e = 0; e < 4; ++e) xv[e] = x4[e * 64 + ln];
  float pj[16];
  #pragma unroll
  for (int j = 0; j < 16; ++j) {
    float a = 0.f;
    #pragma unroll
    for (int e = 0; e < 4; ++e) {
      const float4 w = Wc4[j * 256 + e * 64 + ln];
      a += xv[e].x * w.x + xv[e].y * w.y + xv[e].z * w.z + xv[e].w * w.w;
    }
    pj[j] = a;
  }
  #pragma unroll
  for (int j = 0; j < 16; ++j) {
    #pragma unroll
    for (int off = 1; off < 64; off <<= 1) pj[j] += __shfl_xor(pj[j], off);
  }
  if (ln == 0) {
    float p[16];
    float mx = -3.4e38f;
    #pragma unroll
    for (int j = 0; j < 16; ++j) { p[j] = pj[j] * 10.0f; mx = fmaxf(mx, p[j]); }
    float se = 0.f;
    #pragma unroll
    for (int j = 0; j < 16; ++j) { p[j] = expf(p[j] - mx); se += p[j]; }
    const float inv = 1.0f / se;
    #pragma unroll
    for (int j = 0; j < 16; ++j) p[j] *= inv;
    unsigned int mk = 0;
    for (int it = 0; it < 4; ++it) {
      int bi = 0; float bv = -1.f;
      #pragma unroll
      for (int j = 0; j < 16; ++j)
        if (!((mk >> j) & 1u) && p[j] > bv) { bv = p[j]; bi = j; }
      mk |= 1u << bi;
    }
    float ssum = 0.f;
    #pragma unroll
    for (int j = 0; j < 16; ++j) if ((mk >> j) & 1u) ssum += p[j];
    const float rinv = 1.0f / fmaxf(ssum, 1e-8f);
    #pragma unroll
    for (int j = 0; j < 16; ++j)
      probs[(size_t)token * 16 + j] = ((mk >> j) & 1u) ? p[j] * rinv : 0.f;
  }

  if (s == 0) { if (ln == 0) craw[token] = 0.f; return; }

  unsigned short gbit[16];
  *(uint4*)&gbit[0] = *(const uint4*)(gb + rowo + ln * 16);
  *(uint4*)&gbit[8] = *(const uint4*)(gb + rowo + ln * 16 + 8);
  int ckey[16];
  float asum = 0.f;
  #pragma unroll
  for (int i = 0; i < 16; ++i) {
    const unsigned int b = gbit[i];
    ckey[i] = (b & 0x8000u) ? (int)(b ^ 0xFFFFu) : (int)(b | 0x8000u);
    asum += bf2f(b & 0x7FFFu);
  }
  #pragma unroll
  for (int off = 1; off < 64; off <<= 1) asum += __shfl_xor(asum, off);
  const float strength = tanhf(asum * (1.0f / 1024.0f));
  int kkv = (int)ceilf(strength * 256.0f);
  kkv = min(max(kkv, 1), 1024);

  int lo = 0, hi = 0xFFFF;
  while (lo < hi) {
    const int mid = (lo + hi + 1) >> 1;
    int c = 0;
    #pragma unroll
    for (int i = 0; i < 16; ++i) c += (ckey[i] >= mid);
    #pragma unroll
    for (int off = 1; off < 64; off <<= 1) c += __shfl_xor(c, off);
    if (c >= kkv) lo = mid; else hi = mid - 1;
  }
  const int T = lo;

  int cg = 0, myeq = 0;
  #pragma unroll
  for (int i = 0; i < 16; ++i) { cg += (ckey[i] > T); myeq += (ckey[i] == T); }
  #pragma unroll
  for (int off = 1; off < 64; off <<= 1) cg += __shfl_xor(cg, off);
  int incl = myeq;
  #pragma unroll
  for (int off = 1; off < 64; off <<= 1) {
    const int tt = __shfl_up(incl, off);
    if (ln >= off) incl += tt;
  }
  int ebase = incl - myeq;
  const int keep_eq = kkv - cg;

  unsigned short mB[16], qcB[16], kcB[16], qpB[16], kpB[16];
  *(uint4*)&mB[0]  = *(const uint4*)(mb + rowo + ln * 16);
  *(uint4*)&mB[8]  = *(const uint4*)(mb + rowo + ln * 16 + 8);
  *(uint4*)&qcB[0] = *(const uint4*)(qb + rowo + ln * 16);
  *(uint4*)&qcB[8] = *(const uint4*)(qb + rowo + ln * 16 + 8);
  *(uint4*)&kcB[0] = *(const uint4*)(kb + rowo + ln * 16);
  *(uint4*)&kcB[8] = *(const uint4*)(kb + rowo + ln * 16 + 8);
  *(uint4*)&qpB[0] = *(const uint4*)(qb + rowo - DD + ln * 16);
  *(uint4*)&qpB[8] = *(const uint4*)(qb + rowo - DD + ln * 16 + 8);
  *(uint4*)&kpB[0] = *(const uint4*)(kb + rowo - DD + ln * 16);
  *(uint4*)&kpB[8] = *(const uint4*)(kb + rowo - DD + ln * 16 + 8);

  float accv = 0.f;
  #pragma unroll
  for (int i = 0; i < 16; ++i) {
    const bool kp_ = (ckey[i] > T) || (ckey[i] == T && ebase < keep_eq);
    if (ckey[i] == T) ebase++;
    const unsigned int b = gbit[i];
    const bool gpos = (!(b & 0x8000u)) && (b != 0u);
    if (gpos && kp_) {
      const float tw = bf2f(qpB[i]) * bf2f(kcB[i]) - bf2f(qcB[i]) * bf2f(kpB[i]);
      accv += bf2f(mB[i]) * fabsf(tw);
    }
  }
  #pragma unroll
  for (int off = 1; off < 64; off <<= 1) accv += __shfl_xor(accv, off);
  if (ln == 0) craw[token] = accv * (1.0f / 1024.0f);
}

// ---------------- Phase 3a: quorum sigmoid + codebook shift score ----------------
__global__ __launch_bounds__(256) void quorum_kernel(
    const float* __restrict__ craw, const float* __restrict__ probs,
    float* __restrict__ quorum, float* __restrict__ cb)
{
  const int idx = blockIdx.x * 256 + threadIdx.x;
  const int s = idx & (SS - 1);
  const float c1 = craw[idx];
  const float c0 = (s > 0) ? craw[idx - 1] : 0.f;
  const float c2 = (s < SS - 1) ? craw[idx + 1] : 0.f;
  const float local = (c0 + c1 + c2) / 3.0f;
  quorum[idx] = 1.0f / (1.0f + expf((0.5f - local) * 10.0f));
  float sh = 0.f;
  if (s > 0) {
    #pragma unroll
    for (int j = 0; j < 16; ++j)
      sh += fabsf(probs[(size_t)idx * 16 + j] - probs[(size_t)(idx - 1) * 16 + j]);
  }
  cb[idx] = 0.5f * sh;
}

// ---------------- Phase 3b: per-batch budget top-2048 + final mix ----------------
__global__ __launch_bounds__(64) void final_kernel(
    const float* __restrict__ craw, const float* __restrict__ quorum,
    const float* __restrict__ cb, float* __restrict__ outp)
{
  const int b = blockIdx.x;
  const int ln = threadIdx.x;
  const size_t base = (size_t)b * SS;
  float qv[64]; unsigned int key[64];
  #pragma unroll
  for (int i = 0; i < 64; ++i) {
    qv[i] = quorum[base + ln * 64 + i];
    const unsigned int bb = __float_as_uint(qv[i]);
    key[i] = (bb & 0x80000000u) ? ~bb : (bb | 0x80000000u);
  }
  unsigned int lo = 0u, hi = 0xFFFFFFFFu;
  while (lo < hi) {
    const unsigned int mid = (unsigned int)(((unsigned long long)lo + hi + 1ull) >> 1);
    int c = 0;
    #pragma unroll
    for (int i = 0; i < 64; ++i) c += (key[i] >= mid);
    #pragma unroll
    for (int off = 1; off < 64; off <<= 1) c += __shfl_xor(c, off);
    if (c >= BUDGET) lo = mid; else hi = mid - 1;
  }
  const unsigned int T = lo;
  int cg = 0, myeq = 0;
  #pragma unroll
  for (int i = 0; i < 64; ++i) { cg += (key[i] > T); myeq += (key[i] == T); }
  #pragma unroll
  for (int off = 1; off < 64; off <<= 1) cg += __shfl_xor(cg, off);
  int scan = myeq;
  #pragma unroll
  for (int off = 1; off < 64; off <<= 1) {
    const int nsc = __shfl_up(scan, off);
    if (ln >= off) scan += nsc;
  }
  int ebase = scan - myeq;
  const int keep_eq = BUDGET - cg;
  #pragma unroll
  for (int i = 0; i < 64; ++i) {
    const size_t sidx = base + (size_t)ln * 64 + i;
    const bool kp_ = (key[i] > T) || (key[i] == T && ebase < keep_eq);
    if (key[i] == T) ebase++;
    const float q = kp_ ? qv[i] : 0.f;
    outp[sidx] = 0.7f * (craw[sidx] * (0.5f + 0.5f * q)) + 0.3f * cb[sidx];
  }
}

extern "C" void kernel_launch(void* const* d_in, const int* in_sizes, int n_in,
                              void* d_out, int out_size, void* d_ws, size_t ws_size,
                              hipStream_t stream)
{
  const float* x  = (const float*)d_in[0];
  const float* Wq = (const float*)d_in[1];
  const float* Wk = (const float*)d_in[2];
  const float* Wg = (const float*)d_in[3];
  const float* bg = (const float*)d_in[4];
  const float* Wm = (const float*)d_in[5];
  const float* bm = (const float*)d_in[6];
  const float* Wc = (const float*)d_in[7];
  float* outp = (float*)d_out;
  char* w = (char*)d_ws;

  const size_t SZ_BF = (size_t)MM * DD * 2;        // 32 MB per bf16 intermediate
  const size_t SMALL_OFF = 4 * SZ_BF;              // 134217728
  const size_t SZ_SMALL = 1048576 + 3 * 65536;     // probs + craw/quorum/cb

  unsigned short* qb = (unsigned short*)(w);
  unsigned short* kb = (unsigned short*)(w + SZ_BF);
  unsigned short* gb = (unsigned short*)(w + 2 * SZ_BF);
  unsigned short* mb = (unsigned short*)(w + 3 * SZ_BF);
  char* sm = w + SMALL_OFF;
  float* probs  = (float*)(sm);
  float* craw   = (float*)(sm + 1048576);
  float* quorum = (float*)(sm + 1048576 + 65536);
  float* cbuf   = (float*)(sm + 1048576 + 2 * 65536);

  const size_t need_mid = SMALL_OFF + SZ_SMALL + SZ_BF + (size_t)4 * 1048576 * 2;

  if (ws_size >= need_mid) {
    unsigned short* xb = (unsigned short*)(sm + SZ_SMALL);
    unsigned short* Wb = xb + (size_t)MM * DD;
    convert2_kernel<<<dim3(4096 + 2048), 256, 0, stream>>>(
        x, Wq, Wk, Wg, Wm, Wc, xb, Wb, probs);
    gemm256_kernel<<<dim3(NTOT / 256, MM / 256), 512, 0, stream>>>(
        xb, Wb, bg, bm, qb, kb, gb, mb);
    token_kernel3<<<dim3(MM / 4), 256, 0, stream>>>(qb, kb, gb, mb, craw);
  } else {
    mfma_gemm_fb<<<dim3(NTOT / 128, MM / 128), 256, 0, stream>>>(
        x, Wq, Wk, Wg, Wm, bg, bm, qb, kb, gb, mb);
    token_kernel2<<<dim3(MM / 4), 256, 0, stream>>>(x, Wc, qb, kb, gb, mb, probs, craw);
  }
  quorum_kernel<<<dim3(MM / 256), 256, 0, stream>>>(craw, probs, quorum, cbuf);
  final_kernel<<<dim3(BB), 64, 0, stream>>>(craw, quorum, cbuf, outp);
}

// Round 6
// 277.902 us; speedup vs baseline: 7.5223x; 1.0309x over previous
//
#include <hip/hip_runtime.h>
#include <hip/hip_bf16.h>
#include <cstdint>

// Problem constants
#define BB 4
#define SS 4096
#define DD 1024
#define MM (BB * SS)          // 16384 tokens
#define NTOT 4096             // 4 matrices * 1024 output features
#define BUDGET 2048

typedef __attribute__((ext_vector_type(8))) short short8v;   // 8 bf16 (4 VGPR)
typedef __attribute__((ext_vector_type(4))) float f32x4;

__device__ __forceinline__ float bf2f(unsigned int h) {
  return __uint_as_float(h << 16);
}
__device__ __forceinline__ unsigned short f2bf(float f) {
  unsigned int u = __float_as_uint(f);
  u = u + 0x7FFFu + ((u >> 16) & 1u);   // RNE
  return (unsigned short)(u >> 16);
}
__device__ __forceinline__ unsigned int pkbf(float lo, float hi) {
  float2 f; f.x = lo; f.y = hi;
  __hip_bfloat162 h = __float22bfloat162_rn(f);
  return *(unsigned int*)&h;
}

// ---------------- convert2: bf16 copies of x & W-concat + fused codebook probs ----
__global__ __launch_bounds__(256) void convert2_kernel(
    const float* __restrict__ x,
    const float* __restrict__ Wq, const float* __restrict__ Wk,
    const float* __restrict__ Wg, const float* __restrict__ Wm,
    const float* __restrict__ Wc,
    unsigned short* __restrict__ xb, unsigned short* __restrict__ Wb,
    float* __restrict__ probs)
{
  const int blk = blockIdx.x;
  const int t = threadIdx.x;
  if (blk < 4096) {
    const int wv = t >> 6, ln = t & 63;
    const int token = blk * 4 + wv;
    const size_t rowo = (size_t)token * DD;
    const float4* x4 = (const float4*)(x + rowo);
    const float4* Wc4 = (const float4*)Wc;
    float4 xv[4];
    #pragma unroll
    for (int e = 0; e < 4; ++e) xv[e] = x4[e * 64 + ln];
    uint2* xo = (uint2*)(xb + rowo);
    #pragma unroll
    for (int e = 0; e < 4; ++e) {
      uint2 o; o.x = pkbf(xv[e].x, xv[e].y); o.y = pkbf(xv[e].z, xv[e].w);
      xo[e * 64 + ln] = o;
    }
    float pj[16];
    #pragma unroll
    for (int j = 0; j < 16; ++j) {
      float a = 0.f;
      #pragma unroll
      for (int e = 0; e < 4; ++e) {
        const float4 w = Wc4[j * 256 + e * 64 + ln];
        a += xv[e].x * w.x + xv[e].y * w.y + xv[e].z * w.z + xv[e].w * w.w;
      }
      pj[j] = a;
    }
    #pragma unroll
    for (int j = 0; j < 16; ++j) {
      #pragma unroll
      for (int off = 1; off < 64; off <<= 1) pj[j] += __shfl_xor(pj[j], off);
    }
    if (ln == 0) {
      float p[16];
      float mx = -3.4e38f;
      #pragma unroll
      for (int j = 0; j < 16; ++j) { p[j] = pj[j] * 10.0f; mx = fmaxf(mx, p[j]); }
      float se = 0.f;
      #pragma unroll
      for (int j = 0; j < 16; ++j) { p[j] = expf(p[j] - mx); se += p[j]; }
      const float inv = 1.0f / se;
      #pragma unroll
      for (int j = 0; j < 16; ++j) p[j] *= inv;
      unsigned int mk = 0;
      for (int it = 0; it < 4; ++it) {
        int bi = 0; float bv = -1.f;
        #pragma unroll
        for (int j = 0; j < 16; ++j)
          if (!((mk >> j) & 1u) && p[j] > bv) { bv = p[j]; bi = j; }
        mk |= 1u << bi;
      }
      float ssum = 0.f;
      #pragma unroll
      for (int j = 0; j < 16; ++j) if ((mk >> j) & 1u) ssum += p[j];
      const float rinv = 1.0f / fmaxf(ssum, 1e-8f);
      #pragma unroll
      for (int j = 0; j < 16; ++j)
        probs[(size_t)token * 16 + j] = ((mk >> j) & 1u) ? p[j] * rinv : 0.f;
    }
  } else {
    const size_t off0 = (size_t)(blk - 4096) * 2048 + t * 8;
    const int m = (int)(off0 >> 20);
    const float* Ws = (m == 0) ? Wq : (m == 1) ? Wk : (m == 2) ? Wg : Wm;
    const size_t wo = off0 & 1048575u;
    const float4 a0 = *(const float4*)(Ws + wo);
    const float4 a1 = *(const float4*)(Ws + wo + 4);
    uint4 o;
    o.x = pkbf(a0.x, a0.y); o.y = pkbf(a0.z, a0.w);
    o.z = pkbf(a1.x, a1.y); o.w = pkbf(a1.z, a1.w);
    *(uint4*)(Wb + off0) = o;
  }
}

// ---------------- 256x256 MFMA GEMM, 16 waves (4Mx4N), per-wave 64x64 ----------------
// occupancy-first: acc 64 VGPR/lane -> 4 waves/SIMD (16 waves/CU), vs 2 with the
// 8-wave 128x64 variant (AGPR-inclusive budget, round-5 lesson).
// BK=32, double-buffered 64 KB LDS, counted vmcnt(2), XCD-swizzled blockIdx.
__global__ __launch_bounds__(1024, 4) void gemm256_kernel(
    const unsigned short* __restrict__ xb, const unsigned short* __restrict__ Wb,
    const float* __restrict__ bg, const float* __restrict__ bm,
    unsigned short* __restrict__ qb, unsigned short* __restrict__ kb,
    unsigned short* __restrict__ gb, unsigned short* __restrict__ mb)
{
  __shared__ __align__(16) unsigned short lds[32768];  // 64 KB
  const int t  = threadIdx.x;            // 0..1023
  const int wv = t >> 6, ln = t & 63;    // 16 waves
  const int wr = wv >> 2, wc = wv & 3;   // 4 (M) x 4 (N)
  const int frow = ln & 15, kc = ln >> 4;

  // bijective XCD swizzle: nwg = 1024, 8 XCDs, 128 blocks per chunk
  const int o  = blockIdx.y * 16 + blockIdx.x;
  const int L  = (o & 7) * 128 + (o >> 3);
  const int bx = L & 15, by = L >> 4;
  const int m0 = by * 256;
  const int n0 = bx * 256;
  const int mat = n0 >> 10;
  const int nc0 = n0 & 1023;

  f32x4 acc[4][4];
  #pragma unroll
  for (int i = 0; i < 4; ++i)
    #pragma unroll
    for (int j = 0; j < 4; ++j) { acc[i][j][0]=0.f; acc[i][j][1]=0.f; acc[i][j][2]=0.f; acc[i][j][3]=0.f; }

  // staging: 2 x global_load_lds(16B) per thread per K-tile (A 16KB + B 16KB)
  // thread t -> row t>>2, slot t&3; source k-chunk swizzled (slot ^ row&3)
  const int grow = t >> 2;
  const int gch  = (((t & 3) ^ ((t >> 2) & 3)) << 3);
  auto stage = [&](int buf, int kt) {
    const int k0 = kt << 5;
    const unsigned short* ga = xb + (size_t)(m0 + grow) * DD + k0 + gch;
    const unsigned short* gw = Wb + (size_t)(n0 + grow) * DD + k0 + gch;
    __builtin_amdgcn_global_load_lds(
        (const __attribute__((address_space(1))) void*)ga,
        (__attribute__((address_space(3))) void*)((__attribute__((address_space(3))) char*)lds
            + buf * 32768 + t * 16),
        16, 0, 0);
    __builtin_amdgcn_global_load_lds(
        (const __attribute__((address_space(1))) void*)gw,
        (__attribute__((address_space(3))) void*)((__attribute__((address_space(3))) char*)lds
            + buf * 32768 + 16384 + t * 16),
        16, 0, 0);
  };

  stage(0, 0);
  const int sl = ((kc ^ (frow & 3)) << 3);   // swizzled read slot (ushorts)

  for (int kt = 0; kt < 32; ++kt) {
    const int cur = kt & 1;
    if (kt < 31) {
      stage(cur ^ 1, kt + 1);                              // 4 outstanding
      asm volatile("s_waitcnt vmcnt(2)" ::: "memory");     // tile kt's 2 done
    } else {
      asm volatile("s_waitcnt vmcnt(0)" ::: "memory");
    }
    __builtin_amdgcn_s_barrier();                          // tile kt fully in LDS
    asm volatile("" ::: "memory");

    short8v a[4], b[4];
    #pragma unroll
    for (int i = 0; i < 4; ++i)
      a[i] = *(const short8v*)&lds[cur * 16384 + (wr * 64 + i * 16 + frow) * 32 + sl];
    #pragma unroll
    for (int j = 0; j < 4; ++j)
      b[j] = *(const short8v*)&lds[cur * 16384 + 8192 + (wc * 64 + j * 16 + frow) * 32 + sl];

    #pragma unroll
    for (int i = 0; i < 4; ++i)
      #pragma unroll
      for (int j = 0; j < 4; ++j)
        acc[i][j] = __builtin_amdgcn_mfma_f32_16x16x32_bf16(a[i], b[j], acc[i][j], 0, 0, 0);

    asm volatile("" ::: "memory");                         // pin ds_reads above
    __builtin_amdgcn_s_barrier();                          // done reading buf[cur]
  }

  unsigned short* outp = (mat == 0) ? qb : (mat == 1) ? kb : (mat == 2) ? gb : mb;
  #pragma unroll
  for (int i = 0; i < 4; ++i) {
    #pragma unroll
    for (int j = 0; j < 4; ++j) {
      const int col = nc0 + wc * 64 + j * 16 + frow;
      const float bias = (mat == 2) ? bg[col] : (mat == 3) ? bm[col] : 0.f;
      #pragma unroll
      for (int r = 0; r < 4; ++r) {
        const int row = m0 + wr * 64 + i * 16 + kc * 4 + r;
        float v = acc[i][j][r] + bias;
        if (mat == 3) v = fmaxf(v, 0.0f);
        outp[(size_t)row * DD + col] = f2bf(v);
      }
    }
  }
}

// ---------------- fallback GEMM (ws too small): reg-staged f32->bf16, 128x128 ----
__global__ __launch_bounds__(256) void mfma_gemm_fb(
    const float* __restrict__ x,
    const float* __restrict__ Wq, const float* __restrict__ Wk,
    const float* __restrict__ Wg, const float* __restrict__ Wm,
    const float* __restrict__ bg, const float* __restrict__ bm,
    unsigned short* __restrict__ q_o, unsigned short* __restrict__ k_o,
    unsigned short* __restrict__ g_o, unsigned short* __restrict__ m_o)
{
  __shared__ __align__(16) unsigned short As[128 * 32];
  __shared__ __align__(16) unsigned short Bs[128 * 32];
  const int t  = threadIdx.x;
  const int wv = t >> 6, ln = t & 63;
  const int wr = wv >> 1, wc = wv & 1;
  const int m0 = blockIdx.y * 128;
  const int n0 = blockIdx.x * 128;
  const int mat = n0 >> 10;
  const int nc0 = n0 & 1023;
  const float* __restrict__ Wsrc = (mat == 0) ? Wq : (mat == 1) ? Wk : (mat == 2) ? Wg : Wm;

  f32x4 acc[4][4];
  #pragma unroll
  for (int i = 0; i < 4; ++i)
    #pragma unroll
    for (int j = 0; j < 4; ++j) { acc[i][j][0]=0.f; acc[i][j][1]=0.f; acc[i][j][2]=0.f; acc[i][j][3]=0.f; }

  const int frow = ln & 15, kc = ln >> 4;

  for (int k0 = 0; k0 < DD; k0 += 32) {
    #pragma unroll
    for (int c = 0; c < 2; ++c) {
      const int i = c * 256 + t;
      const int row = i >> 2, colc = i & 3;
      const float* ga = x    + (size_t)(m0 + row) * DD + k0 + (colc << 3);
      const float* gw = Wsrc + (size_t)(nc0 + row) * DD + k0 + (colc << 3);
      const float4 a0 = *(const float4*)ga, a1 = *(const float4*)(ga + 4);
      const float4 b0 = *(const float4*)gw, b1 = *(const float4*)(gw + 4);
      uint4 ao, bo;
      ao.x = pkbf(a0.x, a0.y); ao.y = pkbf(a0.z, a0.w);
      ao.z = pkbf(a1.x, a1.y); ao.w = pkbf(a1.z, a1.w);
      bo.x = pkbf(b0.x, b0.y); bo.y = pkbf(b0.z, b0.w);
      bo.z = pkbf(b1.x, b1.y); bo.w = pkbf(b1.z, b1.w);
      *(uint4*)&As[row * 32 + colc * 8] = ao;
      *(uint4*)&Bs[row * 32 + colc * 8] = bo;
    }
    __syncthreads();
    short8v a[4], b[4];
    #pragma unroll
    for (int i = 0; i < 4; ++i) {
      a[i] = *(const short8v*)&As[(wr * 64 + i * 16 + frow) * 32 + kc * 8];
      b[i] = *(const short8v*)&Bs[(wc * 64 + i * 16 + frow) * 32 + kc * 8];
    }
    #pragma unroll
    for (int i = 0; i < 4; ++i)
      #pragma unroll
      for (int j = 0; j < 4; ++j)
        acc[i][j] = __builtin_amdgcn_mfma_f32_16x16x32_bf16(a[i], b[j], acc[i][j], 0, 0, 0);
    __syncthreads();
  }

  unsigned short* outp = (mat == 0) ? q_o : (mat == 1) ? k_o : (mat == 2) ? g_o : m_o;
  #pragma unroll
  for (int i = 0; i < 4; ++i) {
    #pragma unroll
    for (int j = 0; j < 4; ++j) {
      const int col = nc0 + wc * 64 + j * 16 + frow;
      #pragma unroll
      for (int r = 0; r < 4; ++r) {
        const int row = m0 + wr * 64 + i * 16 + kc * 4 + r;
        float v = acc[i][j][r];
        if (mat == 2) v += bg[col];
        if (mat == 3) v = fmaxf(v + bm[col], 0.0f);
        outp[(size_t)row * DD + col] = f2bf(v);
      }
    }
  }
}

// ---------------- Phase 2 (slim): wave-per-token gate/topk/twist only ----------------
__global__ __launch_bounds__(256) void token_kernel3(
    const unsigned short* __restrict__ qb, const unsigned short* __restrict__ kb,
    const unsigned short* __restrict__ gb, const unsigned short* __restrict__ mb,
    float* __restrict__ craw)
{
  const int wv = threadIdx.x >> 6;
  const int ln = threadIdx.x & 63;
  const int token = blockIdx.x * 4 + wv;
  const int s = token & (SS - 1);
  const size_t rowo = (size_t)token * DD;

  if (s == 0) { if (ln == 0) craw[token] = 0.f; return; }

  unsigned short gbit[16];
  *(uint4*)&gbit[0] = *(const uint4*)(gb + rowo + ln * 16);
  *(uint4*)&gbit[8] = *(const uint4*)(gb + rowo + ln * 16 + 8);
  int ckey[16];
  float asum = 0.f;
  #pragma unroll
  for (int i = 0; i < 16; ++i) {
    const unsigned int b = gbit[i];
    ckey[i] = (b & 0x8000u) ? (int)(b ^ 0xFFFFu) : (int)(b | 0x8000u);
    asum += bf2f(b & 0x7FFFu);
  }
  #pragma unroll
  for (int off = 1; off < 64; off <<= 1) asum += __shfl_xor(asum, off);
  const float strength = tanhf(asum * (1.0f / 1024.0f));
  int kkv = (int)ceilf(strength * 256.0f);
  kkv = min(max(kkv, 1), 1024);

  int lo = 0, hi = 0xFFFF;
  while (lo < hi) {
    const int mid = (lo + hi + 1) >> 1;
    int c = 0;
    #pragma unroll
    for (int i = 0; i < 16; ++i) c += (ckey[i] >= mid);
    #pragma unroll
    for (int off = 1; off < 64; off <<= 1) c += __shfl_xor(c, off);
    if (c >= kkv) lo = mid; else hi = mid - 1;
  }
  const int T = lo;

  int cg = 0, myeq = 0;
  #pragma unroll
  for (int i = 0; i < 16; ++i) { cg += (ckey[i] > T); myeq += (ckey[i] == T); }
  #pragma unroll
  for (int off = 1; off < 64; off <<= 1) cg += __shfl_xor(cg, off);
  int incl = myeq;
  #pragma unroll
  for (int off = 1; off < 64; off <<= 1) {
    const int tt = __shfl_up(incl, off);
    if (ln >= off) incl += tt;
  }
  int ebase = incl - myeq;
  const int keep_eq = kkv - cg;

  unsigned short mB[16], qcB[16], kcB[16], qpB[16], kpB[16];
  *(uint4*)&mB[0]  = *(const uint4*)(mb + rowo + ln * 16);
  *(uint4*)&mB[8]  = *(const uint4*)(mb + rowo + ln * 16 + 8);
  *(uint4*)&qcB[0] = *(const uint4*)(qb + rowo + ln * 16);
  *(uint4*)&qcB[8] = *(const uint4*)(qb + rowo + ln * 16 + 8);
  *(uint4*)&kcB[0] = *(const uint4*)(kb + rowo + ln * 16);
  *(uint4*)&kcB[8] = *(const uint4*)(kb + rowo + ln * 16 + 8);
  *(uint4*)&qpB[0] = *(const uint4*)(qb + rowo - DD + ln * 16);
  *(uint4*)&qpB[8] = *(const uint4*)(qb + rowo - DD + ln * 16 + 8);
  *(uint4*)&kpB[0] = *(const uint4*)(kb + rowo - DD + ln * 16);
  *(uint4*)&kpB[8] = *(const uint4*)(kb + rowo - DD + ln * 16 + 8);

  float accv = 0.f;
  #pragma unroll
  for (int i = 0; i < 16; ++i) {
    const bool kp_ = (ckey[i] > T) || (ckey[i] == T && ebase < keep_eq);
    if (ckey[i] == T) ebase++;
    const unsigned int b = gbit[i];
    const bool gpos = (!(b & 0x8000u)) && (b != 0u);   // g > 0
    if (gpos && kp_) {
      const float tw = bf2f(qpB[i]) * bf2f(kcB[i]) - bf2f(qcB[i]) * bf2f(kpB[i]);
      accv += bf2f(mB[i]) * fabsf(tw);
    }
  }
  #pragma unroll
  for (int off = 1; off < 64; off <<= 1) accv += __shfl_xor(accv, off);
  if (ln == 0) craw[token] = accv * (1.0f / 1024.0f);
}

// ---------------- full token kernel (fallback path only) ----------------
__global__ __launch_bounds__(256) void token_kernel2(
    const float* __restrict__ x, const float* __restrict__ Wc,
    const unsigned short* __restrict__ qb, const unsigned short* __restrict__ kb,
    const unsigned short* __restrict__ gb, const unsigned short* __restrict__ mb,
    float* __restrict__ probs, float* __restrict__ craw)
{
  const int wv = threadIdx.x >> 6;
  const int ln = threadIdx.x & 63;
  const int token = blockIdx.x * 4 + wv;
  const int s = token & (SS - 1);
  const size_t rowo = (size_t)token * DD;

  const float4* x4 = (const float4*)(x + rowo);
  const float4* Wc4 = (const float4*)Wc;
  float4 xv[4];
  #pragma unroll
  for (int e = 0; e < 4; ++e) xv[e] = x4[e * 64 + ln];
  float pj[16];
  #pragma unroll
  for (int j = 0; j < 16; ++j) {
    float a = 0.f;
    #pragma unroll
    for (int e = 0; e < 4; ++e) {
      const float4 w = Wc4[j * 256 + e * 64 + ln];
      a += xv[e].x * w.x + xv[e].y * w.y + xv[e].z * w.z + xv[e].w * w.w;
    }
    pj[j] = a;
  }
  #pragma unroll
  for (int j = 0; j < 16; ++j) {
    #pragma unroll
    for (int off = 1; off < 64; off <<= 1) pj[j] += __shfl_xor(pj[j], off);
  }
  if (ln == 0) {
    float p[16];
    float mx = -3.4e38f;
    #pragma unroll
    for (int j = 0; j < 16; ++j) { p[j] = pj[j] * 10.0f; mx = fmaxf(mx, p[j]); }
    float se = 0.f;
    #pragma unroll
    for (int j = 0; j < 16; ++j) { p[j] = expf(p[j] - mx); se += p[j]; }
    const float inv = 1.0f / se;
    #pragma unroll
    for (int j = 0; j < 16; ++j) p[j] *= inv;
    unsigned int mk = 0;
    for (int it = 0; it < 4; ++it) {
      int bi = 0; float bv = -1.f;
      #pragma unroll
      for (int j = 0; j < 16; ++j)
        if (!((mk >> j) & 1u) && p[j] > bv) { bv = p[j]; bi = j; }
      mk |= 1u << bi;
    }
    float ssum = 0.f;
    #pragma unroll
    for (int j = 0; j < 16; ++j) if ((mk >> j) & 1u) ssum += p[j];
    const float rinv = 1.0f / fmaxf(ssum, 1e-8f);
    #pragma unroll
    for (int j = 0; j < 16; ++j)
      probs[(size_t)token * 16 + j] = ((mk >> j) & 1u) ? p[j] * rinv : 0.f;
  }

  if (s == 0) { if (ln == 0) craw[token] = 0.f; return; }

  unsigned short gbit[16];
  *(uint4*)&gbit[0] = *(const uint4*)(gb + rowo + ln * 16);
  *(uint4*)&gbit[8] = *(const uint4*)(gb + rowo + ln * 16 + 8);
  int ckey[16];
  float asum = 0.f;
  #pragma unroll
  for (int i = 0; i < 16; ++i) {
    const unsigned int b = gbit[i];
    ckey[i] = (b & 0x8000u) ? (int)(b ^ 0xFFFFu) : (int)(b | 0x8000u);
    asum += bf2f(b & 0x7FFFu);
  }
  #pragma unroll
  for (int off = 1; off < 64; off <<= 1) asum += __shfl_xor(asum, off);
  const float strength = tanhf(asum * (1.0f / 1024.0f));
  int kkv = (int)ceilf(strength * 256.0f);
  kkv = min(max(kkv, 1), 1024);

  int lo = 0, hi = 0xFFFF;
  while (lo < hi) {
    const int mid = (lo + hi + 1) >> 1;
    int c = 0;
    #pragma unroll
    for (int i = 0; i < 16; ++i) c += (ckey[i] >= mid);
    #pragma unroll
    for (int off = 1; off < 64; off <<= 1) c += __shfl_xor(c, off);
    if (c >= kkv) lo = mid; else hi = mid - 1;
  }
  const int T = lo;

  int cg = 0, myeq = 0;
  #pragma unroll
  for (int i = 0; i < 16; ++i) { cg += (ckey[i] > T); myeq += (ckey[i] == T); }
  #pragma unroll
  for (int off = 1; off < 64; off <<= 1) cg += __shfl_xor(cg, off);
  int incl = myeq;
  #pragma unroll
  for (int off = 1; off < 64; off <<= 1) {
    const int tt = __shfl_up(incl, off);
    if (ln >= off) incl += tt;
  }
  int ebase = incl - myeq;
  const int keep_eq = kkv - cg;

  unsigned short mB[16], qcB[16], kcB[16], qpB[16], kpB[16];
  *(uint4*)&mB[0]  = *(const uint4*)(mb + rowo + ln * 16);
  *(uint4*)&mB[8]  = *(const uint4*)(mb + rowo + ln * 16 + 8);
  *(uint4*)&qcB[0] = *(const uint4*)(qb + rowo + ln * 16);
  *(uint4*)&qcB[8] = *(const uint4*)(qb + rowo + ln * 16 + 8);
  *(uint4*)&kcB[0] = *(const uint4*)(kb + rowo + ln * 16);
  *(uint4*)&kcB[8] = *(const uint4*)(kb + rowo + ln * 16 + 8);
  *(uint4*)&qpB[0] = *(const uint4*)(qb + rowo - DD + ln * 16);
  *(uint4*)&qpB[8] = *(const uint4*)(qb + rowo - DD + ln * 16 + 8);
  *(uint4*)&kpB[0] = *(const uint4*)(kb + rowo - DD + ln * 16);
  *(uint4*)&kpB[8] = *(const uint4*)(kb + rowo - DD + ln * 16 + 8);

  float accv = 0.f;
  #pragma unroll
  for (int i = 0; i < 16; ++i) {
    const bool kp_ = (ckey[i] > T) || (ckey[i] == T && ebase < keep_eq);
    if (ckey[i] == T) ebase++;
    const unsigned int b = gbit[i];
    const bool gpos = (!(b & 0x8000u)) && (b != 0u);
    if (gpos && kp_) {
      const float tw = bf2f(qpB[i]) * bf2f(kcB[i]) - bf2f(qcB[i]) * bf2f(kpB[i]);
      accv += bf2f(mB[i]) * fabsf(tw);
    }
  }
  #pragma unroll
  for (int off = 1; off < 64; off <<= 1) accv += __shfl_xor(accv, off);
  if (ln == 0) craw[token] = accv * (1.0f / 1024.0f);
}

// ---------------- Phase 3a: quorum sigmoid + codebook shift score ----------------
__global__ __launch_bounds__(256) void quorum_kernel(
    const float* __restrict__ craw, const float* __restrict__ probs,
    float* __restrict__ quorum, float* __restrict__ cb)
{
  const int idx = blockIdx.x * 256 + threadIdx.x;
  const int s = idx & (SS - 1);
  const float c1 = craw[idx];
  const float c0 = (s > 0) ? craw[idx - 1] : 0.f;
  const float c2 = (s < SS - 1) ? craw[idx + 1] : 0.f;
  const float local = (c0 + c1 + c2) / 3.0f;
  quorum[idx] = 1.0f / (1.0f + expf((0.5f - local) * 10.0f));
  float sh = 0.f;
  if (s > 0) {
    #pragma unroll
    for (int j = 0; j < 16; ++j)
      sh += fabsf(probs[(size_t)idx * 16 + j] - probs[(size_t)(idx - 1) * 16 + j]);
  }
  cb[idx] = 0.5f * sh;
}

// ---------------- Phase 3b: per-batch budget top-2048 + final mix ----------------
__global__ __launch_bounds__(64) void final_kernel(
    const float* __restrict__ craw, const float* __restrict__ quorum,
    const float* __restrict__ cb, float* __restrict__ outp)
{
  const int b = blockIdx.x;
  const int ln = threadIdx.x;
  const size_t base = (size_t)b * SS;
  float qv[64]; unsigned int key[64];
  #pragma unroll
  for (int i = 0; i < 64; ++i) {
    qv[i] = quorum[base + ln * 64 + i];
    const unsigned int bb = __float_as_uint(qv[i]);
    key[i] = (bb & 0x80000000u) ? ~bb : (bb | 0x80000000u);
  }
  unsigned int lo = 0u, hi = 0xFFFFFFFFu;
  while (lo < hi) {
    const unsigned int mid = (unsigned int)(((unsigned long long)lo + hi + 1ull) >> 1);
    int c = 0;
    #pragma unroll
    for (int i = 0; i < 64; ++i) c += (key[i] >= mid);
    #pragma unroll
    for (int off = 1; off < 64; off <<= 1) c += __shfl_xor(c, off);
    if (c >= BUDGET) lo = mid; else hi = mid - 1;
  }
  const unsigned int T = lo;
  int cg = 0, myeq = 0;
  #pragma unroll
  for (int i = 0; i < 64; ++i) { cg += (key[i] > T); myeq += (key[i] == T); }
  #pragma unroll
  for (int off = 1; off < 64; off <<= 1) cg += __shfl_xor(cg, off);
  int scan = myeq;
  #pragma unroll
  for (int off = 1; off < 64; off <<= 1) {
    const int nsc = __shfl_up(scan, off);
    if (ln >= off) scan += nsc;
  }
  int ebase = scan - myeq;
  const int keep_eq = BUDGET - cg;
  #pragma unroll
  for (int i = 0; i < 64; ++i) {
    const size_t sidx = base + (size_t)ln * 64 + i;
    const bool kp_ = (key[i] > T) || (key[i] == T && ebase < keep_eq);
    if (key[i] == T) ebase++;
    const float q = kp_ ? qv[i] : 0.f;
    outp[sidx] = 0.7f * (craw[sidx] * (0.5f + 0.5f * q)) + 0.3f * cb[sidx];
  }
}

extern "C" void kernel_launch(void* const* d_in, const int* in_sizes, int n_in,
                              void* d_out, int out_size, void* d_ws, size_t ws_size,
                              hipStream_t stream)
{
  const float* x  = (const float*)d_in[0];
  const float* Wq = (const float*)d_in[1];
  const float* Wk = (const float*)d_in[2];
  const float* Wg = (const float*)d_in[3];
  const float* bg = (const float*)d_in[4];
  const float* Wm = (const float*)d_in[5];
  const float* bm = (const float*)d_in[6];
  const float* Wc = (const float*)d_in[7];
  float* outp = (float*)d_out;
  char* w = (char*)d_ws;

  const size_t SZ_BF = (size_t)MM * DD * 2;        // 32 MB per bf16 intermediate
  const size_t SMALL_OFF = 4 * SZ_BF;              // 134217728
  const size_t SZ_SMALL = 1048576 + 3 * 65536;     // probs + craw/quorum/cb

  unsigned short* qb = (unsigned short*)(w);
  unsigned short* kb = (unsigned short*)(w + SZ_BF);
  unsigned short* gb = (unsigned short*)(w + 2 * SZ_BF);
  unsigned short* mb = (unsigned short*)(w + 3 * SZ_BF);
  char* sm = w + SMALL_OFF;
  float* probs  = (float*)(sm);
  float* craw   = (float*)(sm + 1048576);
  float* quorum = (float*)(sm + 1048576 + 65536);
  float* cbuf   = (float*)(sm + 1048576 + 2 * 65536);

  const size_t need_mid = SMALL_OFF + SZ_SMALL + SZ_BF + (size_t)4 * 1048576 * 2;

  if (ws_size >= need_mid) {
    unsigned short* xb = (unsigned short*)(sm + SZ_SMALL);
    unsigned short* Wb = xb + (size_t)MM * DD;
    convert2_kernel<<<dim3(4096 + 2048), 256, 0, stream>>>(
        x, Wq, Wk, Wg, Wm, Wc, xb, Wb, probs);
    gemm256_kernel<<<dim3(NTOT / 256, MM / 256), 1024, 0, stream>>>(
        xb, Wb, bg, bm, qb, kb, gb, mb);
    token_kernel3<<<dim3(MM / 4), 256, 0, stream>>>(qb, kb, gb, mb, craw);
  } else {
    mfma_gemm_fb<<<dim3(NTOT / 128, MM / 128), 256, 0, stream>>>(
        x, Wq, Wk, Wg, Wm, bg, bm, qb, kb, gb, mb);
    token_kernel2<<<dim3(MM / 4), 256, 0, stream>>>(x, Wc, qb, kb, gb, mb, probs, craw);
  }
  quorum_kernel<<<dim3(MM / 256), 256, 0, stream>>>(craw, probs, quorum, cbuf);
  final_kernel<<<dim3(BB), 64, 0, stream>>>(craw, quorum, cbuf, outp);
}